// Round 3
// baseline (250.557 us; speedup 1.0000x reference)
//
#include <hip/hip_runtime.h>
#include <hip/hip_bf16.h>

#define TOKENS 8192
#define DM 512
#define NE 8
#define HID 1024
#define NSLOT (TOKENS * 2)
#define NB 32          // token blocks for hist/build (256 tokens each)

#define BM 128
#define BN 64
#define BK 64

typedef __bf16 bf16x8 __attribute__((ext_vector_type(8)));
typedef float floatx4 __attribute__((ext_vector_type(4)));
typedef unsigned short u16x8 __attribute__((ext_vector_type(8)));

__device__ __forceinline__ unsigned short f2bf(float f) {
    union { float f; unsigned u; } c; c.f = f;
    unsigned u = c.u;
    u += 0x7fffu + ((u >> 16) & 1u);   // RNE
    return (unsigned short)(u >> 16);
}

// async global->LDS, 16B per lane, LDS dest = wave-uniform base + lane*16
__device__ __forceinline__ void load16_lds(const void* g, void* l) {
    __builtin_amdgcn_global_load_lds(
        (const __attribute__((address_space(1))) unsigned int*)g,
        (__attribute__((address_space(3))) unsigned int*)l, 16, 0, 0);
}

// ---------------- init: zero y (only needed for atomic fallback) ----------------
__global__ void init_kernel(float* __restrict__ y) {
    const size_t n4 = (size_t)TOKENS * DM / 4;
    float4* y4 = (float4*)y;
    for (size_t i = (size_t)blockIdx.x * blockDim.x + threadIdx.x; i < n4;
         i += (size_t)gridDim.x * blockDim.x)
        y4[i] = make_float4(0.f, 0.f, 0.f, 0.f);
}

// ---------------- x fp32 -> bf16 ----------------
__global__ void cvt_x_kernel(const float* __restrict__ src, unsigned short* __restrict__ dst) {
    int i = blockIdx.x * blockDim.x + threadIdx.x;
    const float4* s = (const float4*)src + (size_t)i * 2;
    float4 a = s[0], b = s[1];
    u16x8 r;
    r[0] = f2bf(a.x); r[1] = f2bf(a.y); r[2] = f2bf(a.z); r[3] = f2bf(a.w);
    r[4] = f2bf(b.x); r[5] = f2bf(b.y); r[6] = f2bf(b.z); r[7] = f2bf(b.w);
    *((u16x8*)dst + i) = r;
}

// ------- W [E][K][N] fp32 -> Wt [E][N][K] bf16 (32x32 LDS tile transpose) -------
__global__ void cvt_transpose_kernel(const float* __restrict__ src, unsigned short* __restrict__ dst,
                                     int K, int N) {
    __shared__ float tile[32][33];
    const int tk = K >> 5, tn = N >> 5;
    int b = blockIdx.x;
    int e = b / (tk * tn);
    int rem = b % (tk * tn);
    int kt = rem / tn, nt = rem % tn;
    int tx = threadIdx.x & 31, ty = threadIdx.x >> 5;
    const float* s = src + ((size_t)e * K + kt * 32) * N + nt * 32;
    #pragma unroll
    for (int i = 0; i < 32; i += 8)
        tile[ty + i][tx] = s[(size_t)(ty + i) * N + tx];
    __syncthreads();
    unsigned short* d = dst + ((size_t)e * N + nt * 32) * K + kt * 32;
    #pragma unroll
    for (int i = 0; i < 32; i += 8)
        d[(size_t)(ty + i) * K + tx] = f2bf(tile[tx][ty + i]);
}

// ---------------- router: fp32 logits, top-2, softmax over 2 (no atomics) ---------
__global__ void router_kernel(const float* __restrict__ x, const float* __restrict__ Wg,
                              const float* __restrict__ bg,
                              int* __restrict__ top_idx, float* __restrict__ top_p) {
    int lane = threadIdx.x & 63, wave = threadIdx.x >> 6;
    int t = blockIdx.x * 4 + wave;
    float acc[NE];
    #pragma unroll
    for (int e = 0; e < NE; e++) acc[e] = 0.f;
    const float* xr = x + (size_t)t * DM;
    #pragma unroll
    for (int j = 0; j < 8; j++) {
        int d = lane + j * 64;
        float xv = xr[d];
        const float4* wr = (const float4*)(Wg + (size_t)d * NE);
        float4 w0 = wr[0], w1 = wr[1];
        acc[0] += xv * w0.x; acc[1] += xv * w0.y; acc[2] += xv * w0.z; acc[3] += xv * w0.w;
        acc[4] += xv * w1.x; acc[5] += xv * w1.y; acc[6] += xv * w1.z; acc[7] += xv * w1.w;
    }
    #pragma unroll
    for (int e = 0; e < NE; e++) {
        float v = acc[e];
        #pragma unroll
        for (int off = 32; off > 0; off >>= 1) v += __shfl_down(v, off, 64);
        acc[e] = v;
    }
    if (lane == 0) {
        float best = -1e30f, second = -1e30f;
        int bi = 0, si = 0;
        #pragma unroll
        for (int e = 0; e < NE; e++) {
            float v = acc[e] + bg[e];
            if (v > best) { second = best; si = bi; best = v; bi = e; }
            else if (v > second) { second = v; si = e; }
        }
        float ex = __expf(second - best);
        float inv = 1.f / (1.f + ex);
        top_idx[t * 2] = bi;  top_idx[t * 2 + 1] = si;
        top_p[t * 2] = inv;   top_p[t * 2 + 1] = ex * inv;
    }
}

// ---------------- per-block LDS histogram ----------------
__global__ void hist_kernel(const int* __restrict__ top_idx, int* __restrict__ block_hist) {
    __shared__ int h[NE];
    int b = blockIdx.x, tid = threadIdx.x;
    if (tid < NE) h[tid] = 0;
    __syncthreads();
    int t = b * 256 + tid;
    atomicAdd(&h[top_idx[t * 2]], 1);
    atomicAdd(&h[top_idx[t * 2 + 1]], 1);
    __syncthreads();
    if (tid < NE) block_hist[b * NE + tid] = h[tid];
}

// ---------------- scan: counts, offsets, per-block bases ----------------
__global__ void prefix_kernel(const int* __restrict__ block_hist, int* __restrict__ counts,
                              int* __restrict__ offsets, int* __restrict__ bases) {
    int e = threadIdx.x;
    if (e < NE) {
        int run = 0;
        for (int b = 0; b < NB; b++) { bases[b * NE + e] = run; run += block_hist[b * NE + e]; }
        counts[e] = run;
    }
    __syncthreads();
    if (e == 0) {
        int s = 0;
        for (int ee = 0; ee < NE; ee++) { offsets[ee] = s; s += counts[ee]; }
    }
    __syncthreads();
    if (e < NE) {
        int off = offsets[e];
        for (int b = 0; b < NB; b++) bases[b * NE + e] += off;
    }
}

// ---------------- build compact expert buckets (LDS cursors only) ----------------
__global__ void build_kernel(const int* __restrict__ top_idx, const float* __restrict__ top_p,
                             const int* __restrict__ bases,
                             int* __restrict__ rows, float* __restrict__ gates,
                             int* __restrict__ slot_of) {
    __shared__ int cur[NE];
    int b = blockIdx.x, tid = threadIdx.x;
    if (tid < NE) cur[tid] = bases[b * NE + tid];
    __syncthreads();
    int t = b * 256 + tid;
    #pragma unroll
    for (int k = 0; k < 2; k++) {
        int e = top_idx[t * 2 + k];
        int slot = atomicAdd(&cur[e], 1);
        rows[slot] = t;
        gates[slot] = top_p[t * 2 + k];
        slot_of[t * 2 + k] = slot;
    }
}

// ---------------- GEMM1: H = silu(X*W1) .* (X*W3), bf16 out ----------------
// tile 128(slots) x 64(cols of BOTH W1 and W3), BK=64, global_load_lds staging,
// XOR-swizzled LDS (chunk ^= row&7) for conflict-free ds_read_b128.
__global__ __launch_bounds__(256) void gemm1_kernel(
    const unsigned short* __restrict__ xb,     // [TOKENS][DM]
    const unsigned short* __restrict__ w1t,    // [E][HID][DM]
    const unsigned short* __restrict__ w3t,    // [E][HID][DM]
    unsigned short* __restrict__ Hb,           // [NSLOT][HID]
    const int* __restrict__ rows, const int* __restrict__ counts,
    const int* __restrict__ offsets) {
    const int e = blockIdx.z, mt = blockIdx.y, nt = blockIdx.x;
    const int cnt = counts[e];
    if (mt * BM >= cnt) return;
    const int off = offsets[e];

    __shared__ unsigned short As[BM * BK];     // 16 KB
    __shared__ unsigned short B1s[BN * BK];    // 8 KB
    __shared__ unsigned short B3s[BN * BK];    // 8 KB

    const int tid = threadIdx.x;
    const int lane = tid & 63, wave = tid >> 6;
    const int lrow8 = lane >> 3;               // 0..7
    const int lchunk = (lane & 7) ^ lrow8;     // swizzled global chunk this lane fetches

    // global pointers (per-lane) for the staging instructions
    const unsigned short* a_g[4];
    unsigned short* a_l[4];
    #pragma unroll
    for (int i = 0; i < 4; i++) {
        int r = (wave * 4 + i) * 8 + lrow8;    // 0..127
        int gr = mt * BM + r;
        int tok = rows[off + (gr < cnt ? gr : 0)];
        a_g[i] = xb + (size_t)tok * DM + lchunk * 8;
        a_l[i] = As + (wave * 4 + i) * 512;    // wave-uniform LDS base
    }
    const unsigned short* b1_g[2]; const unsigned short* b3_g[2];
    unsigned short* b1_l[2]; unsigned short* b3_l[2];
    #pragma unroll
    for (int i = 0; i < 2; i++) {
        int r = (wave * 2 + i) * 8 + lrow8;    // 0..63
        b1_g[i] = w1t + ((size_t)e * HID + nt * BN + r) * DM + lchunk * 8;
        b3_g[i] = w3t + ((size_t)e * HID + nt * BN + r) * DM + lchunk * 8;
        b1_l[i] = B1s + (wave * 2 + i) * 512;
        b3_l[i] = B3s + (wave * 2 + i) * 512;
    }

    const int l15 = lane & 15, quad = lane >> 4;
    const int sw = l15 & 7;

    floatx4 acc1[2][4], acc3[2][4];
    #pragma unroll
    for (int i = 0; i < 2; i++)
        #pragma unroll
        for (int j = 0; j < 4; j++) {
            acc1[i][j] = (floatx4){0.f, 0.f, 0.f, 0.f};
            acc3[i][j] = (floatx4){0.f, 0.f, 0.f, 0.f};
        }

    for (int k0 = 0; k0 < DM; k0 += BK) {
        __syncthreads();     // all readers of previous tile done
        #pragma unroll
        for (int i = 0; i < 4; i++) load16_lds(a_g[i] + k0, a_l[i]);
        #pragma unroll
        for (int i = 0; i < 2; i++) {
            load16_lds(b1_g[i] + k0, b1_l[i]);
            load16_lds(b3_g[i] + k0, b3_l[i]);
        }
        __syncthreads();     // staging complete (vmcnt drained by barrier)
        #pragma unroll
        for (int kk = 0; kk < 2; kk++) {
            const int qc = kk * 4 + quad;
            const int ch = (qc ^ sw) << 3;
            bf16x8 af[2], b1f[4], b3f[4];
            #pragma unroll
            for (int mi = 0; mi < 2; mi++)
                af[mi] = *(const bf16x8*)(As + (wave * 32 + mi * 16 + l15) * 64 + ch);
            #pragma unroll
            for (int ni = 0; ni < 4; ni++) {
                b1f[ni] = *(const bf16x8*)(B1s + (ni * 16 + l15) * 64 + ch);
                b3f[ni] = *(const bf16x8*)(B3s + (ni * 16 + l15) * 64 + ch);
            }
            #pragma unroll
            for (int mi = 0; mi < 2; mi++)
                #pragma unroll
                for (int ni = 0; ni < 4; ni++) {
                    acc1[mi][ni] = __builtin_amdgcn_mfma_f32_16x16x32_bf16(af[mi], b1f[ni], acc1[mi][ni], 0, 0, 0);
                    acc3[mi][ni] = __builtin_amdgcn_mfma_f32_16x16x32_bf16(af[mi], b3f[ni], acc3[mi][ni], 0, 0, 0);
                }
        }
    }
    // epilogue: silu(z1)*z3 -> bf16; C/D: col=l15, row=quad*4+r
    #pragma unroll
    for (int mi = 0; mi < 2; mi++) {
        #pragma unroll
        for (int r = 0; r < 4; r++) {
            int mloc = wave * 32 + mi * 16 + quad * 4 + r;
            int gi = mt * BM + mloc;
            if (gi < cnt) {
                size_t rowbase = (size_t)(off + gi) * HID + nt * BN;
                #pragma unroll
                for (int ni = 0; ni < 4; ni++) {
                    float z1 = acc1[mi][ni][r];
                    float z3 = acc3[mi][ni][r];
                    float h = (z1 / (1.f + __expf(-z1))) * z3;
                    Hb[rowbase + ni * 16 + l15] = f2bf(h);
                }
            }
        }
    }
}

// ---------------- GEMM2: P[slot] = gates[slot] * (H[slot] @ W2), fp32 out --------
__global__ __launch_bounds__(256) void gemm2_kernel(
    const unsigned short* __restrict__ Hb,    // [NSLOT][HID]
    const unsigned short* __restrict__ w2t,   // [E][DM][HID]
    float* __restrict__ P,                    // [NSLOT][DM] (gated) or null
    float* __restrict__ y,                    // atomic fallback
    const int* __restrict__ rows, const float* __restrict__ gates,
    const int* __restrict__ counts, const int* __restrict__ offsets) {
    const int e = blockIdx.z, mt = blockIdx.y, nt = blockIdx.x;
    const int cnt = counts[e];
    if (mt * BM >= cnt) return;
    const int off = offsets[e];

    __shared__ unsigned short As[BM * BK];    // 16 KB
    __shared__ unsigned short Bs[BN * BK];    // 8 KB

    const int tid = threadIdx.x;
    const int lane = tid & 63, wave = tid >> 6;
    const int lrow8 = lane >> 3;
    const int lchunk = (lane & 7) ^ lrow8;

    const unsigned short* a_g[4];
    unsigned short* a_l[4];
    #pragma unroll
    for (int i = 0; i < 4; i++) {
        int r = (wave * 4 + i) * 8 + lrow8;
        int sl = off + mt * BM + r;
        if (sl >= NSLOT) sl = NSLOT - 1;      // clamp (ragged tail), value unused
        a_g[i] = Hb + (size_t)sl * HID + lchunk * 8;
        a_l[i] = As + (wave * 4 + i) * 512;
    }
    const unsigned short* b_g[2];
    unsigned short* b_l[2];
    #pragma unroll
    for (int i = 0; i < 2; i++) {
        int r = (wave * 2 + i) * 8 + lrow8;
        b_g[i] = w2t + ((size_t)e * DM + nt * BN + r) * HID + lchunk * 8;
        b_l[i] = Bs + (wave * 2 + i) * 512;
    }

    const int l15 = lane & 15, quad = lane >> 4;
    const int sw = l15 & 7;

    floatx4 acc[2][4];
    #pragma unroll
    for (int i = 0; i < 2; i++)
        #pragma unroll
        for (int j = 0; j < 4; j++) acc[i][j] = (floatx4){0.f, 0.f, 0.f, 0.f};

    for (int k0 = 0; k0 < HID; k0 += BK) {
        __syncthreads();
        #pragma unroll
        for (int i = 0; i < 4; i++) load16_lds(a_g[i] + k0, a_l[i]);
        #pragma unroll
        for (int i = 0; i < 2; i++) load16_lds(b_g[i] + k0, b_l[i]);
        __syncthreads();
        #pragma unroll
        for (int kk = 0; kk < 2; kk++) {
            const int qc = kk * 4 + quad;
            const int ch = (qc ^ sw) << 3;
            bf16x8 af[2], bf[4];
            #pragma unroll
            for (int mi = 0; mi < 2; mi++)
                af[mi] = *(const bf16x8*)(As + (wave * 32 + mi * 16 + l15) * 64 + ch);
            #pragma unroll
            for (int ni = 0; ni < 4; ni++)
                bf[ni] = *(const bf16x8*)(Bs + (ni * 16 + l15) * 64 + ch);
            #pragma unroll
            for (int mi = 0; mi < 2; mi++)
                #pragma unroll
                for (int ni = 0; ni < 4; ni++)
                    acc[mi][ni] = __builtin_amdgcn_mfma_f32_16x16x32_bf16(af[mi], bf[ni], acc[mi][ni], 0, 0, 0);
        }
    }
    const bool direct = (P == nullptr);
    #pragma unroll
    for (int mi = 0; mi < 2; mi++) {
        #pragma unroll
        for (int r = 0; r < 4; r++) {
            int mloc = wave * 32 + mi * 16 + quad * 4 + r;
            int gi = mt * BM + mloc;
            if (gi < cnt) {
                int slot = off + gi;
                float g = gates[slot];
                #pragma unroll
                for (int ni = 0; ni < 4; ni++) {
                    int col = nt * BN + ni * 16 + l15;
                    float v = g * acc[mi][ni][r];
                    if (direct) {
                        int tokr = rows[slot];
                        atomicAdd(&y[(size_t)tokr * DM + col], v);
                    } else {
                        P[(size_t)slot * DM + col] = v;
                    }
                }
            }
        }
    }
}

// ---------------- combine: y[t] = P[s0] + P[s1] (P pre-gated) ----------------
__global__ void combine_kernel(const float* __restrict__ P, const int* __restrict__ slot_of,
                               float* __restrict__ y) {
    int i = blockIdx.x * blockDim.x + threadIdx.x;    // per float4
    int t = i / (DM / 4);
    int c4 = i % (DM / 4);
    int s0 = slot_of[t * 2], s1 = slot_of[t * 2 + 1];
    float4 a = ((const float4*)P)[(size_t)s0 * (DM / 4) + c4];
    float4 b = ((const float4*)P)[(size_t)s1 * (DM / 4) + c4];
    float4 o;
    o.x = a.x + b.x;
    o.y = a.y + b.y;
    o.z = a.z + b.z;
    o.w = a.w + b.w;
    ((float4*)y)[i] = o;
}

extern "C" void kernel_launch(void* const* d_in, const int* in_sizes, int n_in,
                              void* d_out, int out_size, void* d_ws, size_t ws_size,
                              hipStream_t stream) {
    (void)in_sizes; (void)n_in; (void)out_size;
    const float* x  = (const float*)d_in[0];
    const float* Wg = (const float*)d_in[1];
    const float* bg = (const float*)d_in[2];
    const float* W1 = (const float*)d_in[3];
    const float* W3 = (const float*)d_in[4];
    const float* W2 = (const float*)d_in[5];
    float* y = (float*)d_out;

    char* p = (char*)d_ws;
    auto carve = [&](size_t bytes) -> char* {
        char* r = p;
        p += (bytes + 255) & ~(size_t)255;
        return r;
    };
    unsigned short* xb   = (unsigned short*)carve((size_t)TOKENS * DM * 2);
    unsigned short* w1t  = (unsigned short*)carve((size_t)NE * DM * HID * 2);
    unsigned short* w3t  = (unsigned short*)carve((size_t)NE * DM * HID * 2);
    unsigned short* w2t  = (unsigned short*)carve((size_t)NE * HID * DM * 2);
    unsigned short* Hb   = (unsigned short*)carve((size_t)NSLOT * HID * 2);
    int*   rows    = (int*)carve(NSLOT * 4);
    float* gates   = (float*)carve(NSLOT * 4);
    int*   slot_of = (int*)carve(NSLOT * 4);
    int*   tidx    = (int*)carve((size_t)TOKENS * 2 * 4);
    float* tp      = (float*)carve((size_t)TOKENS * 2 * 4);
    int*   counts  = (int*)carve(256);
    int*   offsets = (int*)carve(256);
    int*   bhist   = (int*)carve((size_t)NB * NE * 4);
    int*   bases   = (int*)carve((size_t)NB * NE * 4);
    size_t base_need = (size_t)(p - (char*)d_ws);
    const size_t PBYTES = (size_t)NSLOT * DM * 4;
    float* P = nullptr;
    if (ws_size >= base_need + PBYTES) P = (float*)carve(PBYTES);

    if (P == nullptr)   // atomic-fallback path needs y zeroed
        init_kernel<<<dim3(1024), dim3(256), 0, stream>>>(y);
    cvt_x_kernel<<<dim3((TOKENS * DM / 8) / 256), dim3(256), 0, stream>>>(x, xb);
    cvt_transpose_kernel<<<dim3(NE * (DM / 32) * (HID / 32)), dim3(256), 0, stream>>>(W1, w1t, DM, HID);
    cvt_transpose_kernel<<<dim3(NE * (DM / 32) * (HID / 32)), dim3(256), 0, stream>>>(W3, w3t, DM, HID);
    cvt_transpose_kernel<<<dim3(NE * (HID / 32) * (DM / 32)), dim3(256), 0, stream>>>(W2, w2t, HID, DM);
    router_kernel<<<dim3(TOKENS / 4), dim3(256), 0, stream>>>(x, Wg, bg, tidx, tp);
    hist_kernel<<<dim3(NB), dim3(256), 0, stream>>>(tidx, bhist);
    prefix_kernel<<<dim3(1), dim3(64), 0, stream>>>(bhist, counts, offsets, bases);
    build_kernel<<<dim3(NB), dim3(256), 0, stream>>>(tidx, tp, bases, rows, gates, slot_of);
    gemm1_kernel<<<dim3(HID / BN, NSLOT / BM, NE), dim3(256), 0, stream>>>(xb, w1t, w3t, Hb, rows, counts, offsets);
    gemm2_kernel<<<dim3(DM / BN, NSLOT / BM, NE), dim3(256), 0, stream>>>(Hb, w2t, P, y, rows, gates, counts, offsets);
    if (P != nullptr)
        combine_kernel<<<dim3((TOKENS * DM / 4) / 256), dim3(256), 0, stream>>>(P, slot_of, y);
}

// Round 4
// 241.073 us; speedup vs baseline: 1.0393x; 1.0393x over previous
//
#include <hip/hip_runtime.h>
#include <hip/hip_bf16.h>

#define TOKENS 8192
#define DM 512
#define NE 8
#define HID 1024
#define NSLOT (TOKENS * 2)
#define NB 32          // token blocks for hist/build (256 tokens each)

#define BM 128
#define BN 64
#define BK 64
#define MAXTILE 136    // > sum ceil(counts[e]/BM) worst case (135)

typedef __bf16 bf16x8 __attribute__((ext_vector_type(8)));
typedef float floatx4 __attribute__((ext_vector_type(4)));
typedef unsigned short u16x8 __attribute__((ext_vector_type(8)));

__device__ __forceinline__ unsigned short f2bf(float f) {
    union { float f; unsigned u; } c; c.f = f;
    unsigned u = c.u;
    u += 0x7fffu + ((u >> 16) & 1u);   // RNE
    return (unsigned short)(u >> 16);
}

// async global->LDS, 16B per lane, LDS dest = wave-uniform base + lane*16
__device__ __forceinline__ void load16_lds(const void* g, void* l) {
    __builtin_amdgcn_global_load_lds(
        (const __attribute__((address_space(1))) unsigned int*)g,
        (__attribute__((address_space(3))) unsigned int*)l, 16, 0, 0);
}

// ---------------- init: zero y (only needed for atomic fallback) ----------------
__global__ void init_kernel(float* __restrict__ y) {
    const size_t n4 = (size_t)TOKENS * DM / 4;
    float4* y4 = (float4*)y;
    for (size_t i = (size_t)blockIdx.x * blockDim.x + threadIdx.x; i < n4;
         i += (size_t)gridDim.x * blockDim.x)
        y4[i] = make_float4(0.f, 0.f, 0.f, 0.f);
}

// ------- W [E][K][N] fp32 -> Wt [E][N][K] bf16 (32x32 LDS tile transpose) -------
__global__ void cvt_transpose_kernel(const float* __restrict__ src, unsigned short* __restrict__ dst,
                                     int K, int N) {
    __shared__ float tile[32][33];
    const int tk = K >> 5, tn = N >> 5;
    int b = blockIdx.x;
    int e = b / (tk * tn);
    int rem = b % (tk * tn);
    int kt = rem / tn, nt = rem % tn;
    int tx = threadIdx.x & 31, ty = threadIdx.x >> 5;
    const float* s = src + ((size_t)e * K + kt * 32) * N + nt * 32;
    #pragma unroll
    for (int i = 0; i < 32; i += 8)
        tile[ty + i][tx] = s[(size_t)(ty + i) * N + tx];
    __syncthreads();
    unsigned short* d = dst + ((size_t)e * N + nt * 32) * K + kt * 32;
    #pragma unroll
    for (int i = 0; i < 32; i += 8)
        d[(size_t)(ty + i) * K + tx] = f2bf(tile[tx][ty + i]);
}

// ------- router (fp32 logits, top-2, softmax over 2) + fused x->bf16 conversion ---
__global__ void router_kernel(const float* __restrict__ x, const float* __restrict__ Wg,
                              const float* __restrict__ bg,
                              int* __restrict__ top_idx, float* __restrict__ top_p,
                              unsigned short* __restrict__ xb) {
    int lane = threadIdx.x & 63, wave = threadIdx.x >> 6;
    int t = blockIdx.x * 4 + wave;
    float acc[NE];
    #pragma unroll
    for (int e = 0; e < NE; e++) acc[e] = 0.f;
    const float* xr = x + (size_t)t * DM;
    unsigned short* xbr = xb + (size_t)t * DM;
    #pragma unroll
    for (int j = 0; j < 8; j++) {
        int d = lane + j * 64;
        float xv = xr[d];
        xbr[d] = f2bf(xv);
        const float4* wr = (const float4*)(Wg + (size_t)d * NE);
        float4 w0 = wr[0], w1 = wr[1];
        acc[0] += xv * w0.x; acc[1] += xv * w0.y; acc[2] += xv * w0.z; acc[3] += xv * w0.w;
        acc[4] += xv * w1.x; acc[5] += xv * w1.y; acc[6] += xv * w1.z; acc[7] += xv * w1.w;
    }
    #pragma unroll
    for (int e = 0; e < NE; e++) {
        float v = acc[e];
        #pragma unroll
        for (int off = 32; off > 0; off >>= 1) v += __shfl_down(v, off, 64);
        acc[e] = v;
    }
    if (lane == 0) {
        float best = -1e30f, second = -1e30f;
        int bi = 0, si = 0;
        #pragma unroll
        for (int e = 0; e < NE; e++) {
            float v = acc[e] + bg[e];
            if (v > best) { second = best; si = bi; best = v; bi = e; }
            else if (v > second) { second = v; si = e; }
        }
        float ex = __expf(second - best);
        float inv = 1.f / (1.f + ex);
        top_idx[t * 2] = bi;  top_idx[t * 2 + 1] = si;
        top_p[t * 2] = inv;   top_p[t * 2 + 1] = ex * inv;
    }
}

// ---------------- per-block LDS histogram ----------------
__global__ void hist_kernel(const int* __restrict__ top_idx, int* __restrict__ block_hist) {
    __shared__ int h[NE];
    int b = blockIdx.x, tid = threadIdx.x;
    if (tid < NE) h[tid] = 0;
    __syncthreads();
    int t = b * 256 + tid;
    atomicAdd(&h[top_idx[t * 2]], 1);
    atomicAdd(&h[top_idx[t * 2 + 1]], 1);
    __syncthreads();
    if (tid < NE) block_hist[b * NE + tid] = h[tid];
}

// ---------------- scan: counts, offsets, per-block bases ----------------
__global__ void prefix_kernel(const int* __restrict__ block_hist, int* __restrict__ counts,
                              int* __restrict__ offsets, int* __restrict__ bases) {
    int e = threadIdx.x;
    if (e < NE) {
        int run = 0;
        for (int b = 0; b < NB; b++) { bases[b * NE + e] = run; run += block_hist[b * NE + e]; }
        counts[e] = run;
    }
    __syncthreads();
    if (e == 0) {
        int s = 0;
        for (int ee = 0; ee < NE; ee++) { offsets[ee] = s; s += counts[ee]; }
    }
    __syncthreads();
    if (e < NE) {
        int off = offsets[e];
        for (int b = 0; b < NB; b++) bases[b * NE + e] += off;
    }
}

// ---------------- build compact expert buckets (LDS cursors only) ----------------
__global__ void build_kernel(const int* __restrict__ top_idx, const float* __restrict__ top_p,
                             const int* __restrict__ bases,
                             int* __restrict__ rows, float* __restrict__ gates,
                             int* __restrict__ slot_of) {
    __shared__ int cur[NE];
    int b = blockIdx.x, tid = threadIdx.x;
    if (tid < NE) cur[tid] = bases[b * NE + tid];
    __syncthreads();
    int t = b * 256 + tid;
    #pragma unroll
    for (int k = 0; k < 2; k++) {
        int e = top_idx[t * 2 + k];
        int slot = atomicAdd(&cur[e], 1);
        rows[slot] = t;
        gates[slot] = top_p[t * 2 + k];
        slot_of[t * 2 + k] = slot;
    }
}

// map compact tile id gy -> (expert e, tile mt); returns false past the end
__device__ __forceinline__ bool tile_lookup(const int* counts, const int* offsets, int gy,
                                            int& e, int& mt, int& cnt, int& off) {
    int bacc = 0;
    #pragma unroll
    for (int ee = 0; ee < NE; ee++) {
        int c = counts[ee];
        int ntl = (c + BM - 1) >> 7;
        if (gy < bacc + ntl) { e = ee; mt = gy - bacc; cnt = c; off = offsets[ee]; return true; }
        bacc += ntl;
    }
    return false;
}

// ---------------- GEMM1: H = silu(X*W1) .* (X*W3), bf16 out ----------------
// 128(slots) x 64(cols of BOTH W1,W3), BK=64, double-buffered global_load_lds,
// XOR-swizzled LDS (chunk ^= row&7) -> 0 bank conflicts.
__global__ __launch_bounds__(256) void gemm1_kernel(
    const unsigned short* __restrict__ xb,     // [TOKENS][DM]
    const unsigned short* __restrict__ w1t,    // [E][HID][DM]
    const unsigned short* __restrict__ w3t,    // [E][HID][DM]
    unsigned short* __restrict__ Hb,           // [NSLOT][HID]
    const int* __restrict__ rows, const int* __restrict__ counts,
    const int* __restrict__ offsets) {
    const int nt = blockIdx.x;
    int e, mt, cnt, off;
    if (!tile_lookup(counts, offsets, blockIdx.y, e, mt, cnt, off)) return;

    __shared__ unsigned short As[2][BM * BK];     // 32 KB
    __shared__ unsigned short B1s[2][BN * BK];    // 16 KB
    __shared__ unsigned short B3s[2][BN * BK];    // 16 KB

    const int tid = threadIdx.x;
    const int lane = tid & 63, wave = tid >> 6;
    const int lrow8 = lane >> 3;               // 0..7
    const int lchunk = (lane & 7) ^ lrow8;     // swizzled global chunk this lane fetches

    const unsigned short* a_g[4];
    #pragma unroll
    for (int i = 0; i < 4; i++) {
        int r = (wave * 4 + i) * 8 + lrow8;    // 0..127
        int gr = mt * BM + r;
        int tok = rows[off + (gr < cnt ? gr : 0)];
        a_g[i] = xb + (size_t)tok * DM + lchunk * 8;
    }
    const unsigned short* b1_g[2]; const unsigned short* b3_g[2];
    #pragma unroll
    for (int i = 0; i < 2; i++) {
        int r = (wave * 2 + i) * 8 + lrow8;    // 0..63
        b1_g[i] = w1t + ((size_t)e * HID + nt * BN + r) * DM + lchunk * 8;
        b3_g[i] = w3t + ((size_t)e * HID + nt * BN + r) * DM + lchunk * 8;
    }

    const int l15 = lane & 15, quad = lane >> 4;
    const int sw = l15 & 7;

    floatx4 acc1[2][4], acc3[2][4];
    #pragma unroll
    for (int i = 0; i < 2; i++)
        #pragma unroll
        for (int j = 0; j < 4; j++) {
            acc1[i][j] = (floatx4){0.f, 0.f, 0.f, 0.f};
            acc3[i][j] = (floatx4){0.f, 0.f, 0.f, 0.f};
        }

    auto stage = [&](int k0, int b) {
        #pragma unroll
        for (int i = 0; i < 4; i++) load16_lds(a_g[i] + k0, &As[b][(wave * 4 + i) * 512]);
        #pragma unroll
        for (int i = 0; i < 2; i++) {
            load16_lds(b1_g[i] + k0, &B1s[b][(wave * 2 + i) * 512]);
            load16_lds(b3_g[i] + k0, &B3s[b][(wave * 2 + i) * 512]);
        }
    };
    auto compute = [&](int b) {
        #pragma unroll
        for (int kk = 0; kk < 2; kk++) {
            const int qc = kk * 4 + quad;
            const int ch = (qc ^ sw) << 3;
            bf16x8 af[2], b1f[4], b3f[4];
            #pragma unroll
            for (int mi = 0; mi < 2; mi++)
                af[mi] = *(const bf16x8*)(&As[b][(wave * 32 + mi * 16 + l15) * 64 + ch]);
            #pragma unroll
            for (int ni = 0; ni < 4; ni++) {
                b1f[ni] = *(const bf16x8*)(&B1s[b][(ni * 16 + l15) * 64 + ch]);
                b3f[ni] = *(const bf16x8*)(&B3s[b][(ni * 16 + l15) * 64 + ch]);
            }
            #pragma unroll
            for (int mi = 0; mi < 2; mi++)
                #pragma unroll
                for (int ni = 0; ni < 4; ni++) {
                    acc1[mi][ni] = __builtin_amdgcn_mfma_f32_16x16x32_bf16(af[mi], b1f[ni], acc1[mi][ni], 0, 0, 0);
                    acc3[mi][ni] = __builtin_amdgcn_mfma_f32_16x16x32_bf16(af[mi], b3f[ni], acc3[mi][ni], 0, 0, 0);
                }
        }
    };

    const int NI = DM / BK;   // 8
    stage(0, 0);
    #pragma unroll
    for (int i = 0; i < NI; i += 2) {
        __syncthreads();                        // buf0 staged; prior reads of buf1 done
        if (i + 1 < NI) stage((i + 1) * BK, 1); // prefetch next into buf1
        compute(0);
        __syncthreads();                        // buf1 staged; reads of buf0 done
        if (i + 2 < NI) stage((i + 2) * BK, 0);
        compute(1);
    }
    // epilogue: silu(z1)*z3 -> bf16; C/D: col=l15, row=quad*4+r
    #pragma unroll
    for (int mi = 0; mi < 2; mi++) {
        #pragma unroll
        for (int r = 0; r < 4; r++) {
            int mloc = wave * 32 + mi * 16 + quad * 4 + r;
            int gi = mt * BM + mloc;
            if (gi < cnt) {
                size_t rowbase = (size_t)(off + gi) * HID + nt * BN;
                #pragma unroll
                for (int ni = 0; ni < 4; ni++) {
                    float z1 = acc1[mi][ni][r];
                    float z3 = acc3[mi][ni][r];
                    float h = (z1 / (1.f + __expf(-z1))) * z3;
                    Hb[rowbase + ni * 16 + l15] = f2bf(h);
                }
            }
        }
    }
}

// ---------------- GEMM2: P[slot] = gates[slot] * (H[slot] @ W2), fp32 out --------
__global__ __launch_bounds__(256) void gemm2_kernel(
    const unsigned short* __restrict__ Hb,    // [NSLOT][HID]
    const unsigned short* __restrict__ w2t,   // [E][DM][HID]
    float* __restrict__ P,                    // [NSLOT][DM] (gated) or null
    float* __restrict__ y,                    // atomic fallback
    const int* __restrict__ rows, const float* __restrict__ gates,
    const int* __restrict__ counts, const int* __restrict__ offsets) {
    const int nt = blockIdx.x;
    int e, mt, cnt, off;
    if (!tile_lookup(counts, offsets, blockIdx.y, e, mt, cnt, off)) return;

    __shared__ unsigned short As[2][BM * BK];    // 32 KB
    __shared__ unsigned short Bs[2][BN * BK];    // 16 KB

    const int tid = threadIdx.x;
    const int lane = tid & 63, wave = tid >> 6;
    const int lrow8 = lane >> 3;
    const int lchunk = (lane & 7) ^ lrow8;

    const unsigned short* a_g[4];
    #pragma unroll
    for (int i = 0; i < 4; i++) {
        int r = (wave * 4 + i) * 8 + lrow8;
        int sl = off + mt * BM + r;
        if (sl >= NSLOT) sl = NSLOT - 1;      // clamp (ragged tail), value unused
        a_g[i] = Hb + (size_t)sl * HID + lchunk * 8;
    }
    const unsigned short* b_g[2];
    #pragma unroll
    for (int i = 0; i < 2; i++) {
        int r = (wave * 2 + i) * 8 + lrow8;
        b_g[i] = w2t + ((size_t)e * DM + nt * BN + r) * HID + lchunk * 8;
    }

    const int l15 = lane & 15, quad = lane >> 4;
    const int sw = l15 & 7;

    floatx4 acc[2][4];
    #pragma unroll
    for (int i = 0; i < 2; i++)
        #pragma unroll
        for (int j = 0; j < 4; j++) acc[i][j] = (floatx4){0.f, 0.f, 0.f, 0.f};

    auto stage = [&](int k0, int b) {
        #pragma unroll
        for (int i = 0; i < 4; i++) load16_lds(a_g[i] + k0, &As[b][(wave * 4 + i) * 512]);
        #pragma unroll
        for (int i = 0; i < 2; i++) load16_lds(b_g[i] + k0, &Bs[b][(wave * 2 + i) * 512]);
    };
    auto compute = [&](int b) {
        #pragma unroll
        for (int kk = 0; kk < 2; kk++) {
            const int qc = kk * 4 + quad;
            const int ch = (qc ^ sw) << 3;
            bf16x8 af[2], bf[4];
            #pragma unroll
            for (int mi = 0; mi < 2; mi++)
                af[mi] = *(const bf16x8*)(&As[b][(wave * 32 + mi * 16 + l15) * 64 + ch]);
            #pragma unroll
            for (int ni = 0; ni < 4; ni++)
                bf[ni] = *(const bf16x8*)(&Bs[b][(ni * 16 + l15) * 64 + ch]);
            #pragma unroll
            for (int mi = 0; mi < 2; mi++)
                #pragma unroll
                for (int ni = 0; ni < 4; ni++)
                    acc[mi][ni] = __builtin_amdgcn_mfma_f32_16x16x32_bf16(af[mi], bf[ni], acc[mi][ni], 0, 0, 0);
        }
    };

    const int NI = HID / BK;   // 16
    stage(0, 0);
    #pragma unroll
    for (int i = 0; i < NI; i += 2) {
        __syncthreads();
        if (i + 1 < NI) stage((i + 1) * BK, 1);
        compute(0);
        __syncthreads();
        if (i + 2 < NI) stage((i + 2) * BK, 0);
        compute(1);
    }
    const bool direct = (P == nullptr);
    #pragma unroll
    for (int mi = 0; mi < 2; mi++) {
        #pragma unroll
        for (int r = 0; r < 4; r++) {
            int mloc = wave * 32 + mi * 16 + quad * 4 + r;
            int gi = mt * BM + mloc;
            if (gi < cnt) {
                int slot = off + gi;
                float g = gates[slot];
                #pragma unroll
                for (int ni = 0; ni < 4; ni++) {
                    int col = nt * BN + ni * 16 + l15;
                    float v = g * acc[mi][ni][r];
                    if (direct) {
                        int tokr = rows[slot];
                        atomicAdd(&y[(size_t)tokr * DM + col], v);
                    } else {
                        P[(size_t)slot * DM + col] = v;
                    }
                }
            }
        }
    }
}

// ---------------- combine: y[t] = P[s0] + P[s1] (P pre-gated) ----------------
__global__ void combine_kernel(const float* __restrict__ P, const int* __restrict__ slot_of,
                               float* __restrict__ y) {
    int i = blockIdx.x * blockDim.x + threadIdx.x;    // per float4
    int t = i / (DM / 4);
    int c4 = i % (DM / 4);
    int s0 = slot_of[t * 2], s1 = slot_of[t * 2 + 1];
    float4 a = ((const float4*)P)[(size_t)s0 * (DM / 4) + c4];
    float4 b = ((const float4*)P)[(size_t)s1 * (DM / 4) + c4];
    float4 o;
    o.x = a.x + b.x;
    o.y = a.y + b.y;
    o.z = a.z + b.z;
    o.w = a.w + b.w;
    ((float4*)y)[i] = o;
}

extern "C" void kernel_launch(void* const* d_in, const int* in_sizes, int n_in,
                              void* d_out, int out_size, void* d_ws, size_t ws_size,
                              hipStream_t stream) {
    (void)in_sizes; (void)n_in; (void)out_size;
    const float* x  = (const float*)d_in[0];
    const float* Wg = (const float*)d_in[1];
    const float* bg = (const float*)d_in[2];
    const float* W1 = (const float*)d_in[3];
    const float* W3 = (const float*)d_in[4];
    const float* W2 = (const float*)d_in[5];
    float* y = (float*)d_out;

    char* p = (char*)d_ws;
    auto carve = [&](size_t bytes) -> char* {
        char* r = p;
        p += (bytes + 255) & ~(size_t)255;
        return r;
    };
    unsigned short* xb   = (unsigned short*)carve((size_t)TOKENS * DM * 2);
    unsigned short* w1t  = (unsigned short*)carve((size_t)NE * DM * HID * 2);
    unsigned short* w3t  = (unsigned short*)carve((size_t)NE * DM * HID * 2);
    unsigned short* w2t  = (unsigned short*)carve((size_t)NE * HID * DM * 2);
    unsigned short* Hb   = (unsigned short*)carve((size_t)NSLOT * HID * 2);
    int*   rows    = (int*)carve(NSLOT * 4);
    float* gates   = (float*)carve(NSLOT * 4);
    int*   slot_of = (int*)carve(NSLOT * 4);
    int*   tidx    = (int*)carve((size_t)TOKENS * 2 * 4);
    float* tp      = (float*)carve((size_t)TOKENS * 2 * 4);
    int*   counts  = (int*)carve(256);
    int*   offsets = (int*)carve(256);
    int*   bhist   = (int*)carve((size_t)NB * NE * 4);
    int*   bases   = (int*)carve((size_t)NB * NE * 4);
    size_t base_need = (size_t)(p - (char*)d_ws);
    const size_t PBYTES = (size_t)NSLOT * DM * 4;
    float* P = nullptr;
    if (ws_size >= base_need + PBYTES) P = (float*)carve(PBYTES);

    if (P == nullptr)   // atomic-fallback path needs y zeroed
        init_kernel<<<dim3(1024), dim3(256), 0, stream>>>(y);
    router_kernel<<<dim3(TOKENS / 4), dim3(256), 0, stream>>>(x, Wg, bg, tidx, tp, xb);
    cvt_transpose_kernel<<<dim3(NE * (DM / 32) * (HID / 32)), dim3(256), 0, stream>>>(W1, w1t, DM, HID);
    cvt_transpose_kernel<<<dim3(NE * (DM / 32) * (HID / 32)), dim3(256), 0, stream>>>(W3, w3t, DM, HID);
    cvt_transpose_kernel<<<dim3(NE * (HID / 32) * (DM / 32)), dim3(256), 0, stream>>>(W2, w2t, HID, DM);
    hist_kernel<<<dim3(NB), dim3(256), 0, stream>>>(tidx, bhist);
    prefix_kernel<<<dim3(1), dim3(64), 0, stream>>>(bhist, counts, offsets, bases);
    build_kernel<<<dim3(NB), dim3(256), 0, stream>>>(tidx, tp, bases, rows, gates, slot_of);
    gemm1_kernel<<<dim3(HID / BN, MAXTILE, 1), dim3(256), 0, stream>>>(xb, w1t, w3t, Hb, rows, counts, offsets);
    gemm2_kernel<<<dim3(DM / BN, MAXTILE, 1), dim3(256), 0, stream>>>(Hb, w2t, P, y, rows, gates, counts, offsets);
    if (P != nullptr)
        combine_kernel<<<dim3((TOKENS * DM / 4) / 256), dim3(256), 0, stream>>>(P, slot_of, y);
}

// Round 5
// 237.219 us; speedup vs baseline: 1.0562x; 1.0162x over previous
//
#include <hip/hip_runtime.h>
#include <hip/hip_bf16.h>

#define TOKENS 8192
#define DM 512
#define NE 8
#define HID 1024
#define NSLOT (TOKENS * 2)
#define NB 32          // token blocks for hist/build (256 tokens each)

#define BK 32
// gemm1 tile
#define BM1 128
#define BN1 128
#define MAXTILE1 136   // >= sum ceil(counts[e]/128) worst case
// gemm2 tile
#define BM2 256
#define BN2 128
#define MAXTILE2 72    // >= sum ceil(counts[e]/256) worst case

typedef __bf16 bf16x8 __attribute__((ext_vector_type(8)));
typedef float floatx4 __attribute__((ext_vector_type(4)));
typedef unsigned short u16x8 __attribute__((ext_vector_type(8)));

__device__ __forceinline__ unsigned short f2bf(float f) {
    union { float f; unsigned u; } c; c.f = f;
    unsigned u = c.u;
    u += 0x7fffu + ((u >> 16) & 1u);   // RNE
    return (unsigned short)(u >> 16);
}

// async global->LDS, 16B per lane, LDS dest = wave-uniform base + lane*16
__device__ __forceinline__ void load16_lds(const void* g, void* l) {
    __builtin_amdgcn_global_load_lds(
        (const __attribute__((address_space(1))) unsigned int*)g,
        (__attribute__((address_space(3))) unsigned int*)l, 16, 0, 0);
}

// ---------------- init: zero y (only needed for atomic fallback) ----------------
__global__ void init_kernel(float* __restrict__ y) {
    const size_t n4 = (size_t)TOKENS * DM / 4;
    float4* y4 = (float4*)y;
    for (size_t i = (size_t)blockIdx.x * blockDim.x + threadIdx.x; i < n4;
         i += (size_t)gridDim.x * blockDim.x)
        y4[i] = make_float4(0.f, 0.f, 0.f, 0.f);
}

// ------- all 3 weights [E][K][N] fp32 -> [E][N][K] bf16; blockIdx.y picks which ---
__global__ void cvt_transpose_kernel(const float* __restrict__ W1, const float* __restrict__ W3,
                                     const float* __restrict__ W2,
                                     unsigned short* __restrict__ w1t, unsigned short* __restrict__ w3t,
                                     unsigned short* __restrict__ w2t) {
    __shared__ float tile[32][33];
    const float* src; unsigned short* dst; int K, N;
    if (blockIdx.y == 0)      { src = W1; dst = w1t; K = DM;  N = HID; }
    else if (blockIdx.y == 1) { src = W3; dst = w3t; K = DM;  N = HID; }
    else                      { src = W2; dst = w2t; K = HID; N = DM;  }
    const int tk = K >> 5, tn = N >> 5;
    int b = blockIdx.x;                 // 0 .. NE*tk*tn-1  (== 4096 for all three)
    int e = b / (tk * tn);
    int rem = b % (tk * tn);
    int kt = rem / tn, nt = rem % tn;
    int tx = threadIdx.x & 31, ty = threadIdx.x >> 5;
    const float* s = src + ((size_t)e * K + kt * 32) * N + nt * 32;
    #pragma unroll
    for (int i = 0; i < 32; i += 8)
        tile[ty + i][tx] = s[(size_t)(ty + i) * N + tx];
    __syncthreads();
    unsigned short* d = dst + ((size_t)e * N + nt * 32) * K + kt * 32;
    #pragma unroll
    for (int i = 0; i < 32; i += 8)
        d[(size_t)(ty + i) * K + tx] = f2bf(tile[tx][ty + i]);
}

// ------- router (fp32 logits, top-2, softmax over 2) + fused x->bf16 conversion ---
__global__ void router_kernel(const float* __restrict__ x, const float* __restrict__ Wg,
                              const float* __restrict__ bg,
                              int* __restrict__ top_idx, float* __restrict__ top_p,
                              unsigned short* __restrict__ xb) {
    int lane = threadIdx.x & 63, wave = threadIdx.x >> 6;
    int t = blockIdx.x * 4 + wave;
    float acc[NE];
    #pragma unroll
    for (int e = 0; e < NE; e++) acc[e] = 0.f;
    const float* xr = x + (size_t)t * DM;
    unsigned short* xbr = xb + (size_t)t * DM;
    #pragma unroll
    for (int j = 0; j < 8; j++) {
        int d = lane + j * 64;
        float xv = xr[d];
        xbr[d] = f2bf(xv);
        const float4* wr = (const float4*)(Wg + (size_t)d * NE);
        float4 w0 = wr[0], w1 = wr[1];
        acc[0] += xv * w0.x; acc[1] += xv * w0.y; acc[2] += xv * w0.z; acc[3] += xv * w0.w;
        acc[4] += xv * w1.x; acc[5] += xv * w1.y; acc[6] += xv * w1.z; acc[7] += xv * w1.w;
    }
    #pragma unroll
    for (int e = 0; e < NE; e++) {
        float v = acc[e];
        #pragma unroll
        for (int off = 32; off > 0; off >>= 1) v += __shfl_down(v, off, 64);
        acc[e] = v;
    }
    if (lane == 0) {
        float best = -1e30f, second = -1e30f;
        int bi = 0, si = 0;
        #pragma unroll
        for (int e = 0; e < NE; e++) {
            float v = acc[e] + bg[e];
            if (v > best) { second = best; si = bi; best = v; bi = e; }
            else if (v > second) { second = v; si = e; }
        }
        float ex = __expf(second - best);
        float inv = 1.f / (1.f + ex);
        top_idx[t * 2] = bi;  top_idx[t * 2 + 1] = si;
        top_p[t * 2] = inv;   top_p[t * 2 + 1] = ex * inv;
    }
}

// ---------------- per-block LDS histogram ----------------
__global__ void hist_kernel(const int* __restrict__ top_idx, int* __restrict__ block_hist) {
    __shared__ int h[NE];
    int b = blockIdx.x, tid = threadIdx.x;
    if (tid < NE) h[tid] = 0;
    __syncthreads();
    int t = b * 256 + tid;
    atomicAdd(&h[top_idx[t * 2]], 1);
    atomicAdd(&h[top_idx[t * 2 + 1]], 1);
    __syncthreads();
    if (tid < NE) block_hist[b * NE + tid] = h[tid];
}

// ---------------- scan: counts, offsets, per-block bases ----------------
__global__ void prefix_kernel(const int* __restrict__ block_hist, int* __restrict__ counts,
                              int* __restrict__ offsets, int* __restrict__ bases) {
    int e = threadIdx.x;
    if (e < NE) {
        int run = 0;
        for (int b = 0; b < NB; b++) { bases[b * NE + e] = run; run += block_hist[b * NE + e]; }
        counts[e] = run;
    }
    __syncthreads();
    if (e == 0) {
        int s = 0;
        for (int ee = 0; ee < NE; ee++) { offsets[ee] = s; s += counts[ee]; }
    }
    __syncthreads();
    if (e < NE) {
        int off = offsets[e];
        for (int b = 0; b < NB; b++) bases[b * NE + e] += off;
    }
}

// ---------------- build compact expert buckets (LDS cursors only) ----------------
__global__ void build_kernel(const int* __restrict__ top_idx, const float* __restrict__ top_p,
                             const int* __restrict__ bases,
                             int* __restrict__ rows, float* __restrict__ gates,
                             int* __restrict__ slot_of) {
    __shared__ int cur[NE];
    int b = blockIdx.x, tid = threadIdx.x;
    if (tid < NE) cur[tid] = bases[b * NE + tid];
    __syncthreads();
    int t = b * 256 + tid;
    #pragma unroll
    for (int k = 0; k < 2; k++) {
        int e = top_idx[t * 2 + k];
        int slot = atomicAdd(&cur[e], 1);
        rows[slot] = t;
        gates[slot] = top_p[t * 2 + k];
        slot_of[t * 2 + k] = slot;
    }
}

// map compact tile id gy -> (expert e, tile mt); bmshift = log2(tile M)
__device__ __forceinline__ bool tile_lookup(const int* counts, const int* offsets, int gy,
                                            int bmshift, int& e, int& mt, int& cnt, int& off) {
    int bacc = 0;
    #pragma unroll
    for (int ee = 0; ee < NE; ee++) {
        int c = counts[ee];
        int ntl = (c + (1 << bmshift) - 1) >> bmshift;
        if (gy < bacc + ntl) { e = ee; mt = gy - bacc; cnt = c; off = offsets[ee]; return true; }
        bacc += ntl;
    }
    return false;
}

// ---------------- GEMM1: H = silu(X*W1) .* (X*W3), bf16 out ----------------
// 128x128 dual-B, BK=32, 4 waves of 64x64, double-buffered global_load_lds,
// XOR chunk swizzle: lane loads chunk (lane&3)^((lane>>3)&3); read quad^((l15>>1)&3).
__global__ __launch_bounds__(256, 2) void gemm1_kernel(
    const unsigned short* __restrict__ xb,     // [TOKENS][DM]
    const unsigned short* __restrict__ w1t,    // [E][HID][DM]
    const unsigned short* __restrict__ w3t,    // [E][HID][DM]
    unsigned short* __restrict__ Hb,           // [NSLOT][HID]
    const int* __restrict__ rows, const int* __restrict__ counts,
    const int* __restrict__ offsets) {
    const int nt = blockIdx.x;
    int e, mt, cnt, off;
    if (!tile_lookup(counts, offsets, blockIdx.y, 7, e, mt, cnt, off)) return;

    __shared__ unsigned short As[2][BM1 * BK];   // 2 x 8 KB
    __shared__ unsigned short B1s[2][BN1 * BK];  // 2 x 8 KB
    __shared__ unsigned short B3s[2][BN1 * BK];  // 2 x 8 KB

    const int tid = threadIdx.x;
    const int lane = tid & 63, wave = tid >> 6;
    const int lr = lane >> 2;                    // row within 16-row group
    const int lc = (lane & 3) ^ ((lane >> 3) & 3); // swizzled chunk this lane fetches

    // A: wave stages rows wave*32 + i*16 + lr (gathered tokens)
    const unsigned short* a_g[2];
    #pragma unroll
    for (int i = 0; i < 2; i++) {
        int r = wave * 32 + i * 16 + lr;
        int gr = mt * BM1 + r;
        int tok = rows[off + (gr < cnt ? gr : 0)];
        a_g[i] = xb + (size_t)tok * DM + lc * 8;
    }
    // B1/B3: wave stages N-rows wave*32 + i*16 + lr
    const unsigned short* b1_g[2]; const unsigned short* b3_g[2];
    #pragma unroll
    for (int i = 0; i < 2; i++) {
        int r = wave * 32 + i * 16 + lr;
        b1_g[i] = w1t + ((size_t)e * HID + nt * BN1 + r) * DM + lc * 8;
        b3_g[i] = w3t + ((size_t)e * HID + nt * BN1 + r) * DM + lc * 8;
    }

    const int l15 = lane & 15, quad = lane >> 4;
    const int rsw = (l15 >> 1) & 3;              // read-side swizzle
    const int m0 = (wave >> 1) * 64, n0 = (wave & 1) * 64;

    floatx4 acc1[4][4], acc3[4][4];
    #pragma unroll
    for (int i = 0; i < 4; i++)
        #pragma unroll
        for (int j = 0; j < 4; j++) {
            acc1[i][j] = (floatx4){0.f, 0.f, 0.f, 0.f};
            acc3[i][j] = (floatx4){0.f, 0.f, 0.f, 0.f};
        }

    auto stage = [&](int k0, int b) {
        #pragma unroll
        for (int i = 0; i < 2; i++) {
            load16_lds(a_g[i] + k0, &As[b][(wave * 32 + i * 16) * BK]);
            load16_lds(b1_g[i] + k0, &B1s[b][(wave * 32 + i * 16) * BK]);
            load16_lds(b3_g[i] + k0, &B3s[b][(wave * 32 + i * 16) * BK]);
        }
    };
    auto compute = [&](int b) {
        const int ch = ((quad ^ rsw) << 3);
        bf16x8 af[4], b1f[4], b3f[4];
        #pragma unroll
        for (int mi = 0; mi < 4; mi++)
            af[mi] = *(const bf16x8*)(&As[b][(m0 + mi * 16 + l15) * BK + ch]);
        #pragma unroll
        for (int ni = 0; ni < 4; ni++) {
            b1f[ni] = *(const bf16x8*)(&B1s[b][(n0 + ni * 16 + l15) * BK + ch]);
            b3f[ni] = *(const bf16x8*)(&B3s[b][(n0 + ni * 16 + l15) * BK + ch]);
        }
        #pragma unroll
        for (int mi = 0; mi < 4; mi++)
            #pragma unroll
            for (int ni = 0; ni < 4; ni++) {
                acc1[mi][ni] = __builtin_amdgcn_mfma_f32_16x16x32_bf16(af[mi], b1f[ni], acc1[mi][ni], 0, 0, 0);
                acc3[mi][ni] = __builtin_amdgcn_mfma_f32_16x16x32_bf16(af[mi], b3f[ni], acc3[mi][ni], 0, 0, 0);
            }
    };

    const int NI = DM / BK;   // 16
    stage(0, 0);
    for (int i = 0; i < NI; i += 2) {
        __syncthreads();                        // buf0 staged; prior reads of buf1 done
        if (i + 1 < NI) stage((i + 1) * BK, 1);
        compute(0);
        __syncthreads();                        // buf1 staged; reads of buf0 done
        if (i + 2 < NI) stage((i + 2) * BK, 0);
        compute(1);
    }
    // epilogue: silu(z1)*z3 -> bf16; C/D: col=l15, row=quad*4+r
    #pragma unroll
    for (int mi = 0; mi < 4; mi++) {
        #pragma unroll
        for (int r = 0; r < 4; r++) {
            int mloc = m0 + mi * 16 + quad * 4 + r;
            int gi = mt * BM1 + mloc;
            if (gi < cnt) {
                size_t rowbase = (size_t)(off + gi) * HID + nt * BN1 + n0;
                #pragma unroll
                for (int ni = 0; ni < 4; ni++) {
                    float z1 = acc1[mi][ni][r];
                    float z3 = acc3[mi][ni][r];
                    float h = (z1 / (1.f + __expf(-z1))) * z3;
                    Hb[rowbase + ni * 16 + l15] = f2bf(h);
                }
            }
        }
    }
}

// ---------------- GEMM2: P[slot] = gates[slot] * (H[slot] @ W2), fp32 out --------
// 256x128, BK=32, 8 waves of 64x64 (grid 4x2), double-buffered.
__global__ __launch_bounds__(512, 4) void gemm2_kernel(
    const unsigned short* __restrict__ Hb,    // [NSLOT][HID]
    const unsigned short* __restrict__ w2t,   // [E][DM][HID]
    float* __restrict__ P,                    // [NSLOT][DM] (gated) or null
    float* __restrict__ y,                    // atomic fallback
    const int* __restrict__ rows, const float* __restrict__ gates,
    const int* __restrict__ counts, const int* __restrict__ offsets) {
    const int nt = blockIdx.x;
    int e, mt, cnt, off;
    if (!tile_lookup(counts, offsets, blockIdx.y, 8, e, mt, cnt, off)) return;

    __shared__ unsigned short As[2][BM2 * BK];   // 2 x 16 KB
    __shared__ unsigned short Bs[2][BN2 * BK];   // 2 x 8 KB

    const int tid = threadIdx.x;
    const int lane = tid & 63, wave = tid >> 6;  // 8 waves
    const int lr = lane >> 2;
    const int lc = (lane & 3) ^ ((lane >> 3) & 3);

    const unsigned short* a_g[2];
    #pragma unroll
    for (int i = 0; i < 2; i++) {
        int r = wave * 32 + i * 16 + lr;         // 0..255
        int sl = off + mt * BM2 + r;
        if (sl >= NSLOT) sl = NSLOT - 1;         // clamp (ragged tail), value unused
        a_g[i] = Hb + (size_t)sl * HID + lc * 8;
    }
    const unsigned short* b_g = w2t + ((size_t)e * DM + nt * BN2 + wave * 16 + lr) * HID + lc * 8;

    const int l15 = lane & 15, quad = lane >> 4;
    const int rsw = (l15 >> 1) & 3;
    const int m0 = (wave >> 1) * 64, n0 = (wave & 1) * 64;

    floatx4 acc[4][4];
    #pragma unroll
    for (int i = 0; i < 4; i++)
        #pragma unroll
        for (int j = 0; j < 4; j++) acc[i][j] = (floatx4){0.f, 0.f, 0.f, 0.f};

    auto stage = [&](int k0, int b) {
        #pragma unroll
        for (int i = 0; i < 2; i++)
            load16_lds(a_g[i] + k0, &As[b][(wave * 32 + i * 16) * BK]);
        load16_lds(b_g + k0, &Bs[b][(wave * 16) * BK]);
    };
    auto compute = [&](int b) {
        const int ch = ((quad ^ rsw) << 3);
        bf16x8 af[4], bf[4];
        #pragma unroll
        for (int mi = 0; mi < 4; mi++)
            af[mi] = *(const bf16x8*)(&As[b][(m0 + mi * 16 + l15) * BK + ch]);
        #pragma unroll
        for (int ni = 0; ni < 4; ni++)
            bf[ni] = *(const bf16x8*)(&Bs[b][(n0 + ni * 16 + l15) * BK + ch]);
        #pragma unroll
        for (int mi = 0; mi < 4; mi++)
            #pragma unroll
            for (int ni = 0; ni < 4; ni++)
                acc[mi][ni] = __builtin_amdgcn_mfma_f32_16x16x32_bf16(af[mi], bf[ni], acc[mi][ni], 0, 0, 0);
    };

    const int NI = HID / BK;   // 32
    stage(0, 0);
    for (int i = 0; i < NI; i += 2) {
        __syncthreads();
        if (i + 1 < NI) stage((i + 1) * BK, 1);
        compute(0);
        __syncthreads();
        if (i + 2 < NI) stage((i + 2) * BK, 0);
        compute(1);
    }
    const bool direct = (P == nullptr);
    #pragma unroll
    for (int mi = 0; mi < 4; mi++) {
        #pragma unroll
        for (int r = 0; r < 4; r++) {
            int mloc = m0 + mi * 16 + quad * 4 + r;
            int gi = mt * BM2 + mloc;
            if (gi < cnt) {
                int slot = off + gi;
                float g = gates[slot];
                #pragma unroll
                for (int ni = 0; ni < 4; ni++) {
                    int col = nt * BN2 + n0 + ni * 16 + l15;
                    float v = g * acc[mi][ni][r];
                    if (direct) {
                        int tokr = rows[slot];
                        atomicAdd(&y[(size_t)tokr * DM + col], v);
                    } else {
                        P[(size_t)slot * DM + col] = v;
                    }
                }
            }
        }
    }
}

// ---------------- combine: y[t] = P[s0] + P[s1] (P pre-gated) ----------------
__global__ void combine_kernel(const float* __restrict__ P, const int* __restrict__ slot_of,
                               float* __restrict__ y) {
    int i = blockIdx.x * blockDim.x + threadIdx.x;    // per float4
    int t = i / (DM / 4);
    int c4 = i % (DM / 4);
    int s0 = slot_of[t * 2], s1 = slot_of[t * 2 + 1];
    float4 a = ((const float4*)P)[(size_t)s0 * (DM / 4) + c4];
    float4 b = ((const float4*)P)[(size_t)s1 * (DM / 4) + c4];
    float4 o;
    o.x = a.x + b.x;
    o.y = a.y + b.y;
    o.z = a.z + b.z;
    o.w = a.w + b.w;
    ((float4*)y)[i] = o;
}

extern "C" void kernel_launch(void* const* d_in, const int* in_sizes, int n_in,
                              void* d_out, int out_size, void* d_ws, size_t ws_size,
                              hipStream_t stream) {
    (void)in_sizes; (void)n_in; (void)out_size;
    const float* x  = (const float*)d_in[0];
    const float* Wg = (const float*)d_in[1];
    const float* bg = (const float*)d_in[2];
    const float* W1 = (const float*)d_in[3];
    const float* W3 = (const float*)d_in[4];
    const float* W2 = (const float*)d_in[5];
    float* y = (float*)d_out;

    char* p = (char*)d_ws;
    auto carve = [&](size_t bytes) -> char* {
        char* r = p;
        p += (bytes + 255) & ~(size_t)255;
        return r;
    };
    unsigned short* xb   = (unsigned short*)carve((size_t)TOKENS * DM * 2);
    unsigned short* w1t  = (unsigned short*)carve((size_t)NE * DM * HID * 2);
    unsigned short* w3t  = (unsigned short*)carve((size_t)NE * DM * HID * 2);
    unsigned short* w2t  = (unsigned short*)carve((size_t)NE * HID * DM * 2);
    unsigned short* Hb   = (unsigned short*)carve((size_t)NSLOT * HID * 2);
    int*   rows    = (int*)carve(NSLOT * 4);
    float* gates   = (float*)carve(NSLOT * 4);
    int*   slot_of = (int*)carve(NSLOT * 4);
    int*   tidx    = (int*)carve((size_t)TOKENS * 2 * 4);
    float* tp      = (float*)carve((size_t)TOKENS * 2 * 4);
    int*   counts  = (int*)carve(256);
    int*   offsets = (int*)carve(256);
    int*   bhist   = (int*)carve((size_t)NB * NE * 4);
    int*   bases   = (int*)carve((size_t)NB * NE * 4);
    size_t base_need = (size_t)(p - (char*)d_ws);
    const size_t PBYTES = (size_t)NSLOT * DM * 4;
    float* P = nullptr;
    if (ws_size >= base_need + PBYTES) P = (float*)carve(PBYTES);

    if (P == nullptr)   // atomic-fallback path needs y zeroed
        init_kernel<<<dim3(1024), dim3(256), 0, stream>>>(y);
    router_kernel<<<dim3(TOKENS / 4), dim3(256), 0, stream>>>(x, Wg, bg, tidx, tp, xb);
    cvt_transpose_kernel<<<dim3(NE * 16 * 32, 3), dim3(256), 0, stream>>>(W1, W3, W2, w1t, w3t, w2t);
    hist_kernel<<<dim3(NB), dim3(256), 0, stream>>>(tidx, bhist);
    prefix_kernel<<<dim3(1), dim3(64), 0, stream>>>(bhist, counts, offsets, bases);
    build_kernel<<<dim3(NB), dim3(256), 0, stream>>>(tidx, tp, bases, rows, gates, slot_of);
    gemm1_kernel<<<dim3(HID / BN1, MAXTILE1), dim3(256), 0, stream>>>(xb, w1t, w3t, Hb, rows, counts, offsets);
    gemm2_kernel<<<dim3(DM / BN2, MAXTILE2), dim3(512), 0, stream>>>(Hb, w2t, P, y, rows, gates, counts, offsets);
    if (P != nullptr)
        combine_kernel<<<dim3((TOKENS * DM / 4) / 256), dim3(256), 0, stream>>>(P, slot_of, y);
}

// Round 6
// 232.188 us; speedup vs baseline: 1.0791x; 1.0217x over previous
//
#include <hip/hip_runtime.h>
#include <hip/hip_bf16.h>

#define TOKENS 8192
#define DM 512
#define NE 8
#define HID 1024
#define NSLOT (TOKENS * 2)
#define NB 32          // token blocks for hist/build (256 tokens each)

#define BM 128
#define BN 64
#define BK 64
#define MAXTILE 136    // > sum ceil(counts[e]/BM) worst case (135)

typedef __bf16 bf16x8 __attribute__((ext_vector_type(8)));
typedef float floatx4 __attribute__((ext_vector_type(4)));
typedef unsigned short u16x8 __attribute__((ext_vector_type(8)));

__device__ __forceinline__ unsigned short f2bf(float f) {
    union { float f; unsigned u; } c; c.f = f;
    unsigned u = c.u;
    u += 0x7fffu + ((u >> 16) & 1u);   // RNE
    return (unsigned short)(u >> 16);
}

// async global->LDS, 16B per lane, LDS dest = wave-uniform base + lane*16
__device__ __forceinline__ void load16_lds(const void* g, void* l) {
    __builtin_amdgcn_global_load_lds(
        (const __attribute__((address_space(1))) unsigned int*)g,
        (__attribute__((address_space(3))) unsigned int*)l, 16, 0, 0);
}

// ------- all 3 weights [E][K][N] fp32 -> [E][N][K] bf16; blockIdx.y picks which ---
__global__ void cvt_transpose_kernel(const float* __restrict__ W1, const float* __restrict__ W3,
                                     const float* __restrict__ W2,
                                     unsigned short* __restrict__ w1t, unsigned short* __restrict__ w3t,
                                     unsigned short* __restrict__ w2t) {
    __shared__ float tile[32][33];
    const float* src; unsigned short* dst; int K, N;
    if (blockIdx.y == 0)      { src = W1; dst = w1t; K = DM;  N = HID; }
    else if (blockIdx.y == 1) { src = W3; dst = w3t; K = DM;  N = HID; }
    else                      { src = W2; dst = w2t; K = HID; N = DM;  }
    const int tk = K >> 5, tn = N >> 5;
    int b = blockIdx.x;                 // 0 .. NE*tk*tn-1 (== 4096 for all three)
    int e = b / (tk * tn);
    int rem = b % (tk * tn);
    int kt = rem / tn, nt = rem % tn;
    int tx = threadIdx.x & 31, ty = threadIdx.x >> 5;
    const float* s = src + ((size_t)e * K + kt * 32) * N + nt * 32;
    #pragma unroll
    for (int i = 0; i < 32; i += 8)
        tile[ty + i][tx] = s[(size_t)(ty + i) * N + tx];
    __syncthreads();
    unsigned short* d = dst + ((size_t)e * N + nt * 32) * K + kt * 32;
    #pragma unroll
    for (int i = 0; i < 32; i += 8)
        d[(size_t)(ty + i) * K + tx] = f2bf(tile[tx][ty + i]);
}

// ------- router (fp32 logits, top-2, softmax over 2) + fused x->bf16 conversion ---
__global__ void router_kernel(const float* __restrict__ x, const float* __restrict__ Wg,
                              const float* __restrict__ bg,
                              int* __restrict__ top_idx, float* __restrict__ top_p,
                              unsigned short* __restrict__ xb) {
    int lane = threadIdx.x & 63, wave = threadIdx.x >> 6;
    int t = blockIdx.x * 4 + wave;
    float acc[NE];
    #pragma unroll
    for (int e = 0; e < NE; e++) acc[e] = 0.f;
    const float* xr = x + (size_t)t * DM;
    unsigned short* xbr = xb + (size_t)t * DM;
    #pragma unroll
    for (int j = 0; j < 8; j++) {
        int d = lane + j * 64;
        float xv = xr[d];
        xbr[d] = f2bf(xv);
        const float4* wr = (const float4*)(Wg + (size_t)d * NE);
        float4 w0 = wr[0], w1 = wr[1];
        acc[0] += xv * w0.x; acc[1] += xv * w0.y; acc[2] += xv * w0.z; acc[3] += xv * w0.w;
        acc[4] += xv * w1.x; acc[5] += xv * w1.y; acc[6] += xv * w1.z; acc[7] += xv * w1.w;
    }
    #pragma unroll
    for (int e = 0; e < NE; e++) {
        float v = acc[e];
        #pragma unroll
        for (int off = 32; off > 0; off >>= 1) v += __shfl_down(v, off, 64);
        acc[e] = v;
    }
    if (lane == 0) {
        float best = -1e30f, second = -1e30f;
        int bi = 0, si = 0;
        #pragma unroll
        for (int e = 0; e < NE; e++) {
            float v = acc[e] + bg[e];
            if (v > best) { second = best; si = bi; best = v; bi = e; }
            else if (v > second) { second = v; si = e; }
        }
        float ex = __expf(second - best);
        float inv = 1.f / (1.f + ex);
        top_idx[t * 2] = bi;  top_idx[t * 2 + 1] = si;
        top_p[t * 2] = inv;   top_p[t * 2 + 1] = ex * inv;
    }
}

// ---------------- per-block LDS histogram ----------------
__global__ void hist_kernel(const int* __restrict__ top_idx, int* __restrict__ block_hist) {
    __shared__ int h[NE];
    int b = blockIdx.x, tid = threadIdx.x;
    if (tid < NE) h[tid] = 0;
    __syncthreads();
    int t = b * 256 + tid;
    atomicAdd(&h[top_idx[t * 2]], 1);
    atomicAdd(&h[top_idx[t * 2 + 1]], 1);
    __syncthreads();
    if (tid < NE) block_hist[b * NE + tid] = h[tid];
}

// ---------------- scan: counts, offsets, per-block bases ----------------
__global__ void prefix_kernel(const int* __restrict__ block_hist, int* __restrict__ counts,
                              int* __restrict__ offsets, int* __restrict__ bases) {
    int e = threadIdx.x;
    if (e < NE) {
        int run = 0;
        for (int b = 0; b < NB; b++) { bases[b * NE + e] = run; run += block_hist[b * NE + e]; }
        counts[e] = run;
    }
    __syncthreads();
    if (e == 0) {
        int s = 0;
        for (int ee = 0; ee < NE; ee++) { offsets[ee] = s; s += counts[ee]; }
    }
    __syncthreads();
    if (e < NE) {
        int off = offsets[e];
        for (int b = 0; b < NB; b++) bases[b * NE + e] += off;
    }
}

// ---------------- build compact expert buckets (LDS cursors only) ----------------
__global__ void build_kernel(const int* __restrict__ top_idx, const float* __restrict__ top_p,
                             const int* __restrict__ bases,
                             int* __restrict__ rows, float* __restrict__ gates,
                             int* __restrict__ slot_of) {
    __shared__ int cur[NE];
    int b = blockIdx.x, tid = threadIdx.x;
    if (tid < NE) cur[tid] = bases[b * NE + tid];
    __syncthreads();
    int t = b * 256 + tid;
    #pragma unroll
    for (int k = 0; k < 2; k++) {
        int e = top_idx[t * 2 + k];
        int slot = atomicAdd(&cur[e], 1);
        rows[slot] = t;
        gates[slot] = top_p[t * 2 + k];
        slot_of[t * 2 + k] = slot;
    }
}

// map compact tile id gy -> (expert e, tile mt); returns false past the end
__device__ __forceinline__ bool tile_lookup(const int* counts, const int* offsets, int gy,
                                            int& e, int& mt, int& cnt, int& off) {
    int bacc = 0;
    #pragma unroll
    for (int ee = 0; ee < NE; ee++) {
        int c = counts[ee];
        int ntl = (c + BM - 1) >> 7;
        if (gy < bacc + ntl) { e = ee; mt = gy - bacc; cnt = c; off = offsets[ee]; return true; }
        bacc += ntl;
    }
    return false;
}

// ---------------- GEMM1: H = silu(X*W1) .* (X*W3), bf16 out ----------------
// 128(slots) x 64(cols of BOTH W1,W3), BK=64, double-buffered global_load_lds,
// XOR-swizzled LDS (chunk ^= row&7) -> 0 bank conflicts. (R4 config: best measured.)
__global__ __launch_bounds__(256) void gemm1_kernel(
    const unsigned short* __restrict__ xb,     // [TOKENS][DM]
    const unsigned short* __restrict__ w1t,    // [E][HID][DM]
    const unsigned short* __restrict__ w3t,    // [E][HID][DM]
    unsigned short* __restrict__ Hb,           // [NSLOT][HID]
    const int* __restrict__ rows, const int* __restrict__ counts,
    const int* __restrict__ offsets) {
    const int nt = blockIdx.x;
    int e, mt, cnt, off;
    if (!tile_lookup(counts, offsets, blockIdx.y, e, mt, cnt, off)) return;

    __shared__ unsigned short As[2][BM * BK];     // 32 KB
    __shared__ unsigned short B1s[2][BN * BK];    // 16 KB
    __shared__ unsigned short B3s[2][BN * BK];    // 16 KB

    const int tid = threadIdx.x;
    const int lane = tid & 63, wave = tid >> 6;
    const int lrow8 = lane >> 3;               // 0..7
    const int lchunk = (lane & 7) ^ lrow8;     // swizzled global chunk this lane fetches

    const unsigned short* a_g[4];
    #pragma unroll
    for (int i = 0; i < 4; i++) {
        int r = (wave * 4 + i) * 8 + lrow8;    // 0..127
        int gr = mt * BM + r;
        int tok = rows[off + (gr < cnt ? gr : 0)];
        a_g[i] = xb + (size_t)tok * DM + lchunk * 8;
    }
    const unsigned short* b1_g[2]; const unsigned short* b3_g[2];
    #pragma unroll
    for (int i = 0; i < 2; i++) {
        int r = (wave * 2 + i) * 8 + lrow8;    // 0..63
        b1_g[i] = w1t + ((size_t)e * HID + nt * BN + r) * DM + lchunk * 8;
        b3_g[i] = w3t + ((size_t)e * HID + nt * BN + r) * DM + lchunk * 8;
    }

    const int l15 = lane & 15, quad = lane >> 4;
    const int sw = l15 & 7;

    floatx4 acc1[2][4], acc3[2][4];
    #pragma unroll
    for (int i = 0; i < 2; i++)
        #pragma unroll
        for (int j = 0; j < 4; j++) {
            acc1[i][j] = (floatx4){0.f, 0.f, 0.f, 0.f};
            acc3[i][j] = (floatx4){0.f, 0.f, 0.f, 0.f};
        }

    auto stage = [&](int k0, int b) {
        #pragma unroll
        for (int i = 0; i < 4; i++) load16_lds(a_g[i] + k0, &As[b][(wave * 4 + i) * 512]);
        #pragma unroll
        for (int i = 0; i < 2; i++) {
            load16_lds(b1_g[i] + k0, &B1s[b][(wave * 2 + i) * 512]);
            load16_lds(b3_g[i] + k0, &B3s[b][(wave * 2 + i) * 512]);
        }
    };
    auto compute = [&](int b) {
        #pragma unroll
        for (int kk = 0; kk < 2; kk++) {
            const int qc = kk * 4 + quad;
            const int ch = (qc ^ sw) << 3;
            bf16x8 af[2], b1f[4], b3f[4];
            #pragma unroll
            for (int mi = 0; mi < 2; mi++)
                af[mi] = *(const bf16x8*)(&As[b][(wave * 32 + mi * 16 + l15) * 64 + ch]);
            #pragma unroll
            for (int ni = 0; ni < 4; ni++) {
                b1f[ni] = *(const bf16x8*)(&B1s[b][(ni * 16 + l15) * 64 + ch]);
                b3f[ni] = *(const bf16x8*)(&B3s[b][(ni * 16 + l15) * 64 + ch]);
            }
            #pragma unroll
            for (int mi = 0; mi < 2; mi++)
                #pragma unroll
                for (int ni = 0; ni < 4; ni++) {
                    acc1[mi][ni] = __builtin_amdgcn_mfma_f32_16x16x32_bf16(af[mi], b1f[ni], acc1[mi][ni], 0, 0, 0);
                    acc3[mi][ni] = __builtin_amdgcn_mfma_f32_16x16x32_bf16(af[mi], b3f[ni], acc3[mi][ni], 0, 0, 0);
                }
        }
    };

    const int NI = DM / BK;   // 8
    stage(0, 0);
    #pragma unroll
    for (int i = 0; i < NI; i += 2) {
        __syncthreads();                        // buf0 staged; prior reads of buf1 done
        if (i + 1 < NI) stage((i + 1) * BK, 1); // prefetch next into buf1
        compute(0);
        __syncthreads();                        // buf1 staged; reads of buf0 done
        if (i + 2 < NI) stage((i + 2) * BK, 0);
        compute(1);
    }
    // epilogue: silu(z1)*z3 -> bf16; C/D: col=l15, row=quad*4+r
    #pragma unroll
    for (int mi = 0; mi < 2; mi++) {
        #pragma unroll
        for (int r = 0; r < 4; r++) {
            int mloc = wave * 32 + mi * 16 + quad * 4 + r;
            int gi = mt * BM + mloc;
            if (gi < cnt) {
                size_t rowbase = (size_t)(off + gi) * HID + nt * BN;
                #pragma unroll
                for (int ni = 0; ni < 4; ni++) {
                    float z1 = acc1[mi][ni][r];
                    float z3 = acc3[mi][ni][r];
                    float h = (z1 / (1.f + __expf(-z1))) * z3;
                    Hb[rowbase + ni * 16 + l15] = f2bf(h);
                }
            }
        }
    }
}

// ------- GEMM2: P[slot] = bf16(gates[slot] * (H[slot] @ W2)) — always P, no atomics
__global__ __launch_bounds__(256) void gemm2_kernel(
    const unsigned short* __restrict__ Hb,    // [NSLOT][HID]
    const unsigned short* __restrict__ w2t,   // [E][DM][HID]
    unsigned short* __restrict__ P,           // [NSLOT][DM] bf16, gated
    const float* __restrict__ gates,
    const int* __restrict__ counts, const int* __restrict__ offsets) {
    const int nt = blockIdx.x;
    int e, mt, cnt, off;
    if (!tile_lookup(counts, offsets, blockIdx.y, e, mt, cnt, off)) return;

    __shared__ unsigned short As[2][BM * BK];    // 32 KB
    __shared__ unsigned short Bs[2][BN * BK];    // 16 KB

    const int tid = threadIdx.x;
    const int lane = tid & 63, wave = tid >> 6;
    const int lrow8 = lane >> 3;
    const int lchunk = (lane & 7) ^ lrow8;

    const unsigned short* a_g[4];
    #pragma unroll
    for (int i = 0; i < 4; i++) {
        int r = (wave * 4 + i) * 8 + lrow8;
        int sl = off + mt * BM + r;
        if (sl >= NSLOT) sl = NSLOT - 1;      // clamp (ragged tail), value unused
        a_g[i] = Hb + (size_t)sl * HID + lchunk * 8;
    }
    const unsigned short* b_g[2];
    #pragma unroll
    for (int i = 0; i < 2; i++) {
        int r = (wave * 2 + i) * 8 + lrow8;
        b_g[i] = w2t + ((size_t)e * DM + nt * BN + r) * HID + lchunk * 8;
    }

    const int l15 = lane & 15, quad = lane >> 4;
    const int sw = l15 & 7;

    floatx4 acc[2][4];
    #pragma unroll
    for (int i = 0; i < 2; i++)
        #pragma unroll
        for (int j = 0; j < 4; j++) acc[i][j] = (floatx4){0.f, 0.f, 0.f, 0.f};

    auto stage = [&](int k0, int b) {
        #pragma unroll
        for (int i = 0; i < 4; i++) load16_lds(a_g[i] + k0, &As[b][(wave * 4 + i) * 512]);
        #pragma unroll
        for (int i = 0; i < 2; i++) load16_lds(b_g[i] + k0, &Bs[b][(wave * 2 + i) * 512]);
    };
    auto compute = [&](int b) {
        #pragma unroll
        for (int kk = 0; kk < 2; kk++) {
            const int qc = kk * 4 + quad;
            const int ch = (qc ^ sw) << 3;
            bf16x8 af[2], bf[4];
            #pragma unroll
            for (int mi = 0; mi < 2; mi++)
                af[mi] = *(const bf16x8*)(&As[b][(wave * 32 + mi * 16 + l15) * 64 + ch]);
            #pragma unroll
            for (int ni = 0; ni < 4; ni++)
                bf[ni] = *(const bf16x8*)(&Bs[b][(ni * 16 + l15) * 64 + ch]);
            #pragma unroll
            for (int mi = 0; mi < 2; mi++)
                #pragma unroll
                for (int ni = 0; ni < 4; ni++)
                    acc[mi][ni] = __builtin_amdgcn_mfma_f32_16x16x32_bf16(af[mi], bf[ni], acc[mi][ni], 0, 0, 0);
        }
    };

    const int NI = HID / BK;   // 16
    stage(0, 0);
    #pragma unroll
    for (int i = 0; i < NI; i += 2) {
        __syncthreads();
        if (i + 1 < NI) stage((i + 1) * BK, 1);
        compute(0);
        __syncthreads();
        if (i + 2 < NI) stage((i + 2) * BK, 0);
        compute(1);
    }
    #pragma unroll
    for (int mi = 0; mi < 2; mi++) {
        #pragma unroll
        for (int r = 0; r < 4; r++) {
            int mloc = wave * 32 + mi * 16 + quad * 4 + r;
            int gi = mt * BM + mloc;
            if (gi < cnt) {
                int slot = off + gi;
                float g = gates[slot];
                #pragma unroll
                for (int ni = 0; ni < 4; ni++) {
                    int col = nt * BN + ni * 16 + l15;
                    P[(size_t)slot * DM + col] = f2bf(g * acc[mi][ni][r]);
                }
            }
        }
    }
}

// ---------------- combine: y[t] = P[s0] + P[s1] (P bf16, pre-gated) ----------------
__global__ void combine_kernel(const unsigned short* __restrict__ P,
                               const int* __restrict__ slot_of, float* __restrict__ y) {
    int i = blockIdx.x * blockDim.x + threadIdx.x;    // per 8 elems
    int t = i / (DM / 8);
    int c8 = i % (DM / 8);
    int s0 = slot_of[t * 2], s1 = slot_of[t * 2 + 1];
    uint4 a = *(const uint4*)(P + (size_t)s0 * DM + c8 * 8);
    uint4 b = *(const uint4*)(P + (size_t)s1 * DM + c8 * 8);
    float o[8];
    const unsigned* aw = (const unsigned*)&a;
    const unsigned* bw = (const unsigned*)&b;
    #pragma unroll
    for (int j = 0; j < 4; j++) {
        union { unsigned u; float f; } al, ah, bl, bh;
        al.u = aw[j] << 16; ah.u = aw[j] & 0xffff0000u;
        bl.u = bw[j] << 16; bh.u = bw[j] & 0xffff0000u;
        o[j * 2]     = al.f + bl.f;
        o[j * 2 + 1] = ah.f + bh.f;
    }
    float4* yo = (float4*)(y + (size_t)t * DM + c8 * 8);
    yo[0] = make_float4(o[0], o[1], o[2], o[3]);
    yo[1] = make_float4(o[4], o[5], o[6], o[7]);
}

extern "C" void kernel_launch(void* const* d_in, const int* in_sizes, int n_in,
                              void* d_out, int out_size, void* d_ws, size_t ws_size,
                              hipStream_t stream) {
    (void)in_sizes; (void)n_in; (void)out_size; (void)ws_size;
    const float* x  = (const float*)d_in[0];
    const float* Wg = (const float*)d_in[1];
    const float* bg = (const float*)d_in[2];
    const float* W1 = (const float*)d_in[3];
    const float* W3 = (const float*)d_in[4];
    const float* W2 = (const float*)d_in[5];
    float* y = (float*)d_out;

    char* p = (char*)d_ws;
    auto carve = [&](size_t bytes) -> char* {
        char* r = p;
        p += (bytes + 255) & ~(size_t)255;
        return r;
    };
    unsigned short* xb   = (unsigned short*)carve((size_t)TOKENS * DM * 2);
    unsigned short* w1t  = (unsigned short*)carve((size_t)NE * DM * HID * 2);   // 8 MB
    unsigned short* w3t  = (unsigned short*)carve((size_t)NE * DM * HID * 2);   // 8 MB (contiguous after w1t)
    unsigned short* w2t  = (unsigned short*)carve((size_t)NE * HID * DM * 2);
    unsigned short* Hb   = (unsigned short*)carve((size_t)NSLOT * HID * 2);
    int*   rows    = (int*)carve(NSLOT * 4);
    float* gates   = (float*)carve(NSLOT * 4);
    int*   slot_of = (int*)carve(NSLOT * 4);
    int*   tidx    = (int*)carve((size_t)TOKENS * 2 * 4);
    float* tp      = (float*)carve((size_t)TOKENS * 2 * 4);
    int*   counts  = (int*)carve(256);
    int*   offsets = (int*)carve(256);
    int*   bhist   = (int*)carve((size_t)NB * NE * 4);
    int*   bases   = (int*)carve((size_t)NB * NE * 4);
    // P (bf16, 16 MB) aliases w1t+w3t (16 MB) — dead after gemm1 completes.
    unsigned short* P = w1t;

    router_kernel<<<dim3(TOKENS / 4), dim3(256), 0, stream>>>(x, Wg, bg, tidx, tp, xb);
    cvt_transpose_kernel<<<dim3(NE * 16 * 32, 3), dim3(256), 0, stream>>>(W1, W3, W2, w1t, w3t, w2t);
    hist_kernel<<<dim3(NB), dim3(256), 0, stream>>>(tidx, bhist);
    prefix_kernel<<<dim3(1), dim3(64), 0, stream>>>(bhist, counts, offsets, bases);
    build_kernel<<<dim3(NB), dim3(256), 0, stream>>>(tidx, tp, bases, rows, gates, slot_of);
    gemm1_kernel<<<dim3(HID / BN, MAXTILE), dim3(256), 0, stream>>>(xb, w1t, w3t, Hb, rows, counts, offsets);
    gemm2_kernel<<<dim3(DM / BN, MAXTILE), dim3(256), 0, stream>>>(Hb, w2t, P, gates, counts, offsets);
    combine_kernel<<<dim3((TOKENS * DM / 8) / 256), dim3(256), 0, stream>>>(P, slot_of, y);
}

// Round 7
// 216.332 us; speedup vs baseline: 1.1582x; 1.0733x over previous
//
#include <hip/hip_runtime.h>
#include <hip/hip_bf16.h>

#define TOKENS 8192
#define DM 512
#define NE 8
#define HID 1024
#define NSLOT (TOKENS * 2)
#define NB 32          // token blocks for hist/build (256 tokens each)

#define BM 128
#define BN 64
#define BK 64
#define MAXTILE 136    // 8 * 17, > sum ceil(counts[e]/BM) worst case (135)

typedef __bf16 bf16x8 __attribute__((ext_vector_type(8)));
typedef float floatx4 __attribute__((ext_vector_type(4)));
typedef unsigned short u16x8 __attribute__((ext_vector_type(8)));

__device__ __forceinline__ unsigned short f2bf(float f) {
    union { float f; unsigned u; } c; c.f = f;
    unsigned u = c.u;
    u += 0x7fffu + ((u >> 16) & 1u);   // RNE
    return (unsigned short)(u >> 16);
}

// async global->LDS, 16B per lane, LDS dest = wave-uniform base + lane*16
__device__ __forceinline__ void load16_lds(const void* g, void* l) {
    __builtin_amdgcn_global_load_lds(
        (const __attribute__((address_space(1))) unsigned int*)g,
        (__attribute__((address_space(3))) unsigned int*)l, 16, 0, 0);
}

// ------- all 3 weights [E][K][N] fp32 -> [E][N][K] bf16; 64x64 tiles,
// uint4 (8-bf16) stores -> 128 B write segments. blockIdx.y picks the weight. ---
__global__ void cvt_transpose_kernel(const float* __restrict__ W1, const float* __restrict__ W3,
                                     const float* __restrict__ W2,
                                     unsigned short* __restrict__ w1t, unsigned short* __restrict__ w3t,
                                     unsigned short* __restrict__ w2t) {
    __shared__ float tile[64][65];
    const float* src; unsigned short* dst; int K, N;
    if (blockIdx.y == 0)      { src = W1; dst = w1t; K = DM;  N = HID; }
    else if (blockIdx.y == 1) { src = W3; dst = w3t; K = DM;  N = HID; }
    else                      { src = W2; dst = w2t; K = HID; N = DM;  }
    const int tkn = (K >> 6) * (N >> 6);     // 128 for all three
    int b = blockIdx.x;                      // 0 .. NE*tkn-1 (== 1024)
    int e = b / tkn;
    int rem = b % tkn;
    const int tn6 = N >> 6;
    int kt = rem / tn6, nt = rem % tn6;
    int tx = threadIdx.x & 15, ty = threadIdx.x >> 4;   // 16 x 16
    const float* s = src + ((size_t)(e * K + kt * 64 + ty)) * N + nt * 64 + tx * 4;
    #pragma unroll
    for (int i = 0; i < 4; i++) {
        float4 v = *(const float4*)(s + (size_t)(i * 16) * N);
        float* tr = &tile[ty + i * 16][tx * 4];
        tr[0] = v.x; tr[1] = v.y; tr[2] = v.z; tr[3] = v.w;
    }
    __syncthreads();
    int n = threadIdx.x >> 3;                // 0..31
    int c8 = (threadIdx.x & 7) * 8;          // k offset within tile
    unsigned short* d = dst + ((size_t)(e * N + nt * 64)) * K + kt * 64;
    #pragma unroll
    for (int i = 0; i < 2; i++) {
        int nn = n + i * 32;
        u16x8 r;
        #pragma unroll
        for (int kk = 0; kk < 8; kk++) r[kk] = f2bf(tile[c8 + kk][nn]);
        *(u16x8*)(d + (size_t)nn * K + c8) = r;
    }
}

// ------- router (fp32 logits, top-2, softmax over 2) + fused x->bf16 conversion ---
__global__ void router_kernel(const float* __restrict__ x, const float* __restrict__ Wg,
                              const float* __restrict__ bg,
                              int* __restrict__ top_idx, float* __restrict__ top_p,
                              unsigned short* __restrict__ xb) {
    int lane = threadIdx.x & 63, wave = threadIdx.x >> 6;
    int t = blockIdx.x * 4 + wave;
    float acc[NE];
    #pragma unroll
    for (int e = 0; e < NE; e++) acc[e] = 0.f;
    const float* xr = x + (size_t)t * DM;
    unsigned short* xbr = xb + (size_t)t * DM;
    #pragma unroll
    for (int j = 0; j < 8; j++) {
        int d = lane + j * 64;
        float xv = xr[d];
        xbr[d] = f2bf(xv);
        const float4* wr = (const float4*)(Wg + (size_t)d * NE);
        float4 w0 = wr[0], w1 = wr[1];
        acc[0] += xv * w0.x; acc[1] += xv * w0.y; acc[2] += xv * w0.z; acc[3] += xv * w0.w;
        acc[4] += xv * w1.x; acc[5] += xv * w1.y; acc[6] += xv * w1.z; acc[7] += xv * w1.w;
    }
    #pragma unroll
    for (int e = 0; e < NE; e++) {
        float v = acc[e];
        #pragma unroll
        for (int off = 32; off > 0; off >>= 1) v += __shfl_down(v, off, 64);
        acc[e] = v;
    }
    if (lane == 0) {
        float best = -1e30f, second = -1e30f;
        int bi = 0, si = 0;
        #pragma unroll
        for (int e = 0; e < NE; e++) {
            float v = acc[e] + bg[e];
            if (v > best) { second = best; si = bi; best = v; bi = e; }
            else if (v > second) { second = v; si = e; }
        }
        float ex = __expf(second - best);
        float inv = 1.f / (1.f + ex);
        top_idx[t * 2] = bi;  top_idx[t * 2 + 1] = si;
        top_p[t * 2] = inv;   top_p[t * 2 + 1] = ex * inv;
    }
}

// ---------------- per-block LDS histogram ----------------
__global__ void hist_kernel(const int* __restrict__ top_idx, int* __restrict__ block_hist) {
    __shared__ int h[NE];
    int b = blockIdx.x, tid = threadIdx.x;
    if (tid < NE) h[tid] = 0;
    __syncthreads();
    int t = b * 256 + tid;
    atomicAdd(&h[top_idx[t * 2]], 1);
    atomicAdd(&h[top_idx[t * 2 + 1]], 1);
    __syncthreads();
    if (tid < NE) block_hist[b * NE + tid] = h[tid];
}

// ---------------- scan: counts, offsets, per-block bases ----------------
__global__ void prefix_kernel(const int* __restrict__ block_hist, int* __restrict__ counts,
                              int* __restrict__ offsets, int* __restrict__ bases) {
    int e = threadIdx.x;
    if (e < NE) {
        int run = 0;
        for (int b = 0; b < NB; b++) { bases[b * NE + e] = run; run += block_hist[b * NE + e]; }
        counts[e] = run;
    }
    __syncthreads();
    if (e == 0) {
        int s = 0;
        for (int ee = 0; ee < NE; ee++) { offsets[ee] = s; s += counts[ee]; }
    }
    __syncthreads();
    if (e < NE) {
        int off = offsets[e];
        for (int b = 0; b < NB; b++) bases[b * NE + e] += off;
    }
}

// ---------------- build compact expert buckets (LDS cursors only) ----------------
__global__ void build_kernel(const int* __restrict__ top_idx, const float* __restrict__ top_p,
                             const int* __restrict__ bases,
                             int* __restrict__ rows, float* __restrict__ gates,
                             int* __restrict__ slot_of) {
    __shared__ int cur[NE];
    int b = blockIdx.x, tid = threadIdx.x;
    if (tid < NE) cur[tid] = bases[b * NE + tid];
    __syncthreads();
    int t = b * 256 + tid;
    #pragma unroll
    for (int k = 0; k < 2; k++) {
        int e = top_idx[t * 2 + k];
        int slot = atomicAdd(&cur[e], 1);
        rows[slot] = t;
        gates[slot] = top_p[t * 2 + k];
        slot_of[t * 2 + k] = slot;
    }
}

// map compact tile id gy -> (expert e, tile mt); returns false past the end
__device__ __forceinline__ bool tile_lookup(const int* counts, const int* offsets, int gy,
                                            int& e, int& mt, int& cnt, int& off) {
    int bacc = 0;
    #pragma unroll
    for (int ee = 0; ee < NE; ee++) {
        int c = counts[ee];
        int ntl = (c + BM - 1) >> 7;
        if (gy < bacc + ntl) { e = ee; mt = gy - bacc; cnt = c; off = offsets[ee]; return true; }
        bacc += ntl;
    }
    return false;
}

// ---------------- GEMM1: H = silu(X*W1) .* (X*W3), bf16 out ----------------
// 128(slots) x 64(cols of BOTH W1,W3), BK=64, double-buffered global_load_lds,
// XOR-swizzled LDS -> 0 bank conflicts. XCD y-slab swizzle: xcd=lid&7 owns a
// contiguous slab of 17 M-tiles (~one expert) so weights live in ONE XCD L2.
__global__ __launch_bounds__(256) void gemm1_kernel(
    const unsigned short* __restrict__ xb,     // [TOKENS][DM]
    const unsigned short* __restrict__ w1t,    // [E][HID][DM]
    const unsigned short* __restrict__ w3t,    // [E][HID][DM]
    unsigned short* __restrict__ Hb,           // [NSLOT][HID]
    const int* __restrict__ rows, const int* __restrict__ counts,
    const int* __restrict__ offsets) {
    const int lid = blockIdx.x;                // 0 .. 16*MAXTILE-1
    const int xcd = lid & 7;
    const int j = lid >> 3;                    // 0..271
    const int gy = xcd * (MAXTILE / 8) + (j >> 4);
    const int nt = j & 15;
    int e, mt, cnt, off;
    if (!tile_lookup(counts, offsets, gy, e, mt, cnt, off)) return;

    __shared__ unsigned short As[2][BM * BK];     // 32 KB
    __shared__ unsigned short B1s[2][BN * BK];    // 16 KB
    __shared__ unsigned short B3s[2][BN * BK];    // 16 KB

    const int tid = threadIdx.x;
    const int lane = tid & 63, wave = tid >> 6;
    const int lrow8 = lane >> 3;               // 0..7
    const int lchunk = (lane & 7) ^ lrow8;     // swizzled global chunk this lane fetches

    const unsigned short* a_g[4];
    #pragma unroll
    for (int i = 0; i < 4; i++) {
        int r = (wave * 4 + i) * 8 + lrow8;    // 0..127
        int gr = mt * BM + r;
        int tok = rows[off + (gr < cnt ? gr : 0)];
        a_g[i] = xb + (size_t)tok * DM + lchunk * 8;
    }
    const unsigned short* b1_g[2]; const unsigned short* b3_g[2];
    #pragma unroll
    for (int i = 0; i < 2; i++) {
        int r = (wave * 2 + i) * 8 + lrow8;    // 0..63
        b1_g[i] = w1t + ((size_t)e * HID + nt * BN + r) * DM + lchunk * 8;
        b3_g[i] = w3t + ((size_t)e * HID + nt * BN + r) * DM + lchunk * 8;
    }

    const int l15 = lane & 15, quad = lane >> 4;
    const int sw = l15 & 7;

    floatx4 acc1[2][4], acc3[2][4];
    #pragma unroll
    for (int i = 0; i < 2; i++)
        #pragma unroll
        for (int j2 = 0; j2 < 4; j2++) {
            acc1[i][j2] = (floatx4){0.f, 0.f, 0.f, 0.f};
            acc3[i][j2] = (floatx4){0.f, 0.f, 0.f, 0.f};
        }

    auto stage = [&](int k0, int b) {
        #pragma unroll
        for (int i = 0; i < 4; i++) load16_lds(a_g[i] + k0, &As[b][(wave * 4 + i) * 512]);
        #pragma unroll
        for (int i = 0; i < 2; i++) {
            load16_lds(b1_g[i] + k0, &B1s[b][(wave * 2 + i) * 512]);
            load16_lds(b3_g[i] + k0, &B3s[b][(wave * 2 + i) * 512]);
        }
    };
    auto compute = [&](int b) {
        #pragma unroll
        for (int kk = 0; kk < 2; kk++) {
            const int qc = kk * 4 + quad;
            const int ch = (qc ^ sw) << 3;
            bf16x8 af[2], b1f[4], b3f[4];
            #pragma unroll
            for (int mi = 0; mi < 2; mi++)
                af[mi] = *(const bf16x8*)(&As[b][(wave * 32 + mi * 16 + l15) * 64 + ch]);
            #pragma unroll
            for (int ni = 0; ni < 4; ni++) {
                b1f[ni] = *(const bf16x8*)(&B1s[b][(ni * 16 + l15) * 64 + ch]);
                b3f[ni] = *(const bf16x8*)(&B3s[b][(ni * 16 + l15) * 64 + ch]);
            }
            #pragma unroll
            for (int mi = 0; mi < 2; mi++)
                #pragma unroll
                for (int ni = 0; ni < 4; ni++) {
                    acc1[mi][ni] = __builtin_amdgcn_mfma_f32_16x16x32_bf16(af[mi], b1f[ni], acc1[mi][ni], 0, 0, 0);
                    acc3[mi][ni] = __builtin_amdgcn_mfma_f32_16x16x32_bf16(af[mi], b3f[ni], acc3[mi][ni], 0, 0, 0);
                }
        }
    };

    const int NI = DM / BK;   // 8
    stage(0, 0);
    #pragma unroll
    for (int i = 0; i < NI; i += 2) {
        __syncthreads();                        // buf0 staged; prior reads of buf1 done
        if (i + 1 < NI) stage((i + 1) * BK, 1); // prefetch next into buf1
        compute(0);
        __syncthreads();                        // buf1 staged; reads of buf0 done
        if (i + 2 < NI) stage((i + 2) * BK, 0);
        compute(1);
    }
    // epilogue: silu(z1)*z3 -> bf16; C/D: col=l15, row=quad*4+r
    #pragma unroll
    for (int mi = 0; mi < 2; mi++) {
        #pragma unroll
        for (int r = 0; r < 4; r++) {
            int mloc = wave * 32 + mi * 16 + quad * 4 + r;
            int gi = mt * BM + mloc;
            if (gi < cnt) {
                size_t rowbase = (size_t)(off + gi) * HID + nt * BN;
                #pragma unroll
                for (int ni = 0; ni < 4; ni++) {
                    float z1 = acc1[mi][ni][r];
                    float z3 = acc3[mi][ni][r];
                    float h = (z1 / (1.f + __expf(-z1))) * z3;
                    Hb[rowbase + ni * 16 + l15] = f2bf(h);
                }
            }
        }
    }
}

// ------- GEMM2: P[slot] = bf16(gates[slot] * (H[slot] @ W2)) — no atomics --------
__global__ __launch_bounds__(256) void gemm2_kernel(
    const unsigned short* __restrict__ Hb,    // [NSLOT][HID]
    const unsigned short* __restrict__ w2t,   // [E][DM][HID]
    unsigned short* __restrict__ P,           // [NSLOT][DM] bf16, gated
    const float* __restrict__ gates,
    const int* __restrict__ counts, const int* __restrict__ offsets) {
    const int lid = blockIdx.x;                // 0 .. 8*MAXTILE-1
    const int xcd = lid & 7;
    const int j = lid >> 3;                    // 0..135
    const int gy = xcd * (MAXTILE / 8) + (j >> 3);
    const int nt = j & 7;
    int e, mt, cnt, off;
    if (!tile_lookup(counts, offsets, gy, e, mt, cnt, off)) return;

    __shared__ unsigned short As[2][BM * BK];    // 32 KB
    __shared__ unsigned short Bs[2][BN * BK];    // 16 KB

    const int tid = threadIdx.x;
    const int lane = tid & 63, wave = tid >> 6;
    const int lrow8 = lane >> 3;
    const int lchunk = (lane & 7) ^ lrow8;

    const unsigned short* a_g[4];
    #pragma unroll
    for (int i = 0; i < 4; i++) {
        int r = (wave * 4 + i) * 8 + lrow8;
        int sl = off + mt * BM + r;
        if (sl >= NSLOT) sl = NSLOT - 1;      // clamp (ragged tail), value unused
        a_g[i] = Hb + (size_t)sl * HID + lchunk * 8;
    }
    const unsigned short* b_g[2];
    #pragma unroll
    for (int i = 0; i < 2; i++) {
        int r = (wave * 2 + i) * 8 + lrow8;
        b_g[i] = w2t + ((size_t)e * DM + nt * BN + r) * HID + lchunk * 8;
    }

    const int l15 = lane & 15, quad = lane >> 4;
    const int sw = l15 & 7;

    floatx4 acc[2][4];
    #pragma unroll
    for (int i = 0; i < 2; i++)
        #pragma unroll
        for (int j2 = 0; j2 < 4; j2++) acc[i][j2] = (floatx4){0.f, 0.f, 0.f, 0.f};

    auto stage = [&](int k0, int b) {
        #pragma unroll
        for (int i = 0; i < 4; i++) load16_lds(a_g[i] + k0, &As[b][(wave * 4 + i) * 512]);
        #pragma unroll
        for (int i = 0; i < 2; i++) load16_lds(b_g[i] + k0, &Bs[b][(wave * 2 + i) * 512]);
    };
    auto compute = [&](int b) {
        #pragma unroll
        for (int kk = 0; kk < 2; kk++) {
            const int qc = kk * 4 + quad;
            const int ch = (qc ^ sw) << 3;
            bf16x8 af[2], bf[4];
            #pragma unroll
            for (int mi = 0; mi < 2; mi++)
                af[mi] = *(const bf16x8*)(&As[b][(wave * 32 + mi * 16 + l15) * 64 + ch]);
            #pragma unroll
            for (int ni = 0; ni < 4; ni++)
                bf[ni] = *(const bf16x8*)(&Bs[b][(ni * 16 + l15) * 64 + ch]);
            #pragma unroll
            for (int mi = 0; mi < 2; mi++)
                #pragma unroll
                for (int ni = 0; ni < 4; ni++)
                    acc[mi][ni] = __builtin_amdgcn_mfma_f32_16x16x32_bf16(af[mi], bf[ni], acc[mi][ni], 0, 0, 0);
        }
    };

    const int NI = HID / BK;   // 16
    stage(0, 0);
    #pragma unroll
    for (int i = 0; i < NI; i += 2) {
        __syncthreads();
        if (i + 1 < NI) stage((i + 1) * BK, 1);
        compute(0);
        __syncthreads();
        if (i + 2 < NI) stage((i + 2) * BK, 0);
        compute(1);
    }
    #pragma unroll
    for (int mi = 0; mi < 2; mi++) {
        #pragma unroll
        for (int r = 0; r < 4; r++) {
            int mloc = wave * 32 + mi * 16 + quad * 4 + r;
            int gi = mt * BM + mloc;
            if (gi < cnt) {
                int slot = off + gi;
                float g = gates[slot];
                #pragma unroll
                for (int ni = 0; ni < 4; ni++) {
                    int col = nt * BN + ni * 16 + l15;
                    P[(size_t)slot * DM + col] = f2bf(g * acc[mi][ni][r]);
                }
            }
        }
    }
}

// ---------------- combine: y[t] = P[s0] + P[s1] (P bf16, pre-gated) ----------------
__global__ void combine_kernel(const unsigned short* __restrict__ P,
                               const int* __restrict__ slot_of, float* __restrict__ y) {
    int i = blockIdx.x * blockDim.x + threadIdx.x;    // per 8 elems
    int t = i / (DM / 8);
    int c8 = i % (DM / 8);
    int s0 = slot_of[t * 2], s1 = slot_of[t * 2 + 1];
    uint4 a = *(const uint4*)(P + (size_t)s0 * DM + c8 * 8);
    uint4 b = *(const uint4*)(P + (size_t)s1 * DM + c8 * 8);
    float o[8];
    const unsigned* aw = (const unsigned*)&a;
    const unsigned* bw = (const unsigned*)&b;
    #pragma unroll
    for (int j = 0; j < 4; j++) {
        union { unsigned u; float f; } al, ah, bl, bh;
        al.u = aw[j] << 16; ah.u = aw[j] & 0xffff0000u;
        bl.u = bw[j] << 16; bh.u = bw[j] & 0xffff0000u;
        o[j * 2]     = al.f + bl.f;
        o[j * 2 + 1] = ah.f + bh.f;
    }
    float4* yo = (float4*)(y + (size_t)t * DM + c8 * 8);
    yo[0] = make_float4(o[0], o[1], o[2], o[3]);
    yo[1] = make_float4(o[4], o[5], o[6], o[7]);
}

extern "C" void kernel_launch(void* const* d_in, const int* in_sizes, int n_in,
                              void* d_out, int out_size, void* d_ws, size_t ws_size,
                              hipStream_t stream) {
    (void)in_sizes; (void)n_in; (void)out_size; (void)ws_size;
    const float* x  = (const float*)d_in[0];
    const float* Wg = (const float*)d_in[1];
    const float* bg = (const float*)d_in[2];
    const float* W1 = (const float*)d_in[3];
    const float* W3 = (const float*)d_in[4];
    const float* W2 = (const float*)d_in[5];
    float* y = (float*)d_out;

    char* p = (char*)d_ws;
    auto carve = [&](size_t bytes) -> char* {
        char* r = p;
        p += (bytes + 255) & ~(size_t)255;
        return r;
    };
    unsigned short* xb   = (unsigned short*)carve((size_t)TOKENS * DM * 2);
    unsigned short* w1t  = (unsigned short*)carve((size_t)NE * DM * HID * 2);   // 8 MB
    unsigned short* w3t  = (unsigned short*)carve((size_t)NE * DM * HID * 2);   // 8 MB (contiguous after w1t)
    unsigned short* w2t  = (unsigned short*)carve((size_t)NE * HID * DM * 2);
    unsigned short* Hb   = (unsigned short*)carve((size_t)NSLOT * HID * 2);
    int*   rows    = (int*)carve(NSLOT * 4);
    float* gates   = (float*)carve(NSLOT * 4);
    int*   slot_of = (int*)carve(NSLOT * 4);
    int*   tidx    = (int*)carve((size_t)TOKENS * 2 * 4);
    float* tp      = (float*)carve((size_t)TOKENS * 2 * 4);
    int*   counts  = (int*)carve(256);
    int*   offsets = (int*)carve(256);
    int*   bhist   = (int*)carve((size_t)NB * NE * 4);
    int*   bases   = (int*)carve((size_t)NB * NE * 4);
    // P (bf16, 16 MB) aliases w1t+w3t (16 MB) — dead after gemm1 completes.
    unsigned short* P = w1t;

    router_kernel<<<dim3(TOKENS / 4), dim3(256), 0, stream>>>(x, Wg, bg, tidx, tp, xb);
    cvt_transpose_kernel<<<dim3(NE * 8 * 16, 3), dim3(256), 0, stream>>>(W1, W3, W2, w1t, w3t, w2t);
    hist_kernel<<<dim3(NB), dim3(256), 0, stream>>>(tidx, bhist);
    prefix_kernel<<<dim3(1), dim3(64), 0, stream>>>(bhist, counts, offsets, bases);
    build_kernel<<<dim3(NB), dim3(256), 0, stream>>>(tidx, tp, bases, rows, gates, slot_of);
    gemm1_kernel<<<dim3((HID / BN) * MAXTILE), dim3(256), 0, stream>>>(xb, w1t, w3t, Hb, rows, counts, offsets);
    gemm2_kernel<<<dim3((DM / BN) * MAXTILE), dim3(256), 0, stream>>>(Hb, w2t, P, gates, counts, offsets);
    combine_kernel<<<dim3((TOKENS * DM / 8) / 256), dim3(256), 0, stream>>>(P, slot_of, y);
}